// Round 4
// baseline (266.374 us; speedup 1.0000x reference)
//
#include <hip/hip_runtime.h>
#include <math.h>

// Problem constants (from reference)
#define KK     500   // info bits
#define MM     500   // parity checks
#define NNODES 1000  // N = K + M variable nodes
#define NSYM   250   // N / BPS
#define NITERS 5
#define MAXVDEG 4    // info vars degree exactly 3 (row weight of P), parity vars 1
#define EMAX   2048  // E = 2000 slots (unpadded), round up
#define TB     256

// XOR bank swizzle on sT indices: involution, bijective on [0,2048).
// Spreads power-of-2 slot strides (sorted checks, d_total=4 dominant) across
// bank pairs; applied via packed slot ids (pass-1/decide, free) and inline
// in pass-2 (2 VALU/access).
#define SWZ(s) ((s) ^ (((s) >> 4) & 3))

// ---------------- setup: graph build + bit packing + bf output -------------
// Checks COUNTING-SORTED by total degree and relabeled (new id = rank):
// waves in BP pass-2 get uniform trip counts (no divergence).  Layout is
// UNPADDED (20 KB LDS total in k_fused -> 8 blocks/CU); bank spread comes
// from the SWZ index swizzle instead of padding.
__global__ void __launch_bounds__(512)
k_setup(const int* __restrict__ cn, const int* __restrict__ vn, int E,
        const float* __restrict__ ebno, const int* __restrict__ P,
        const int* __restrict__ b, int ncw,
        int* __restrict__ cinfo, int* __restrict__ vlist, int* __restrict__ coff,
        int* __restrict__ cdend, int* __restrict__ cperm,
        double* __restrict__ nobuf, unsigned* __restrict__ Ppack,
        unsigned* __restrict__ bpack, float* __restrict__ out, int packBlocks) {
  __shared__ int sdeg[512];   // orig check -> total degree
  __shared__ int scinv[512];  // orig check -> new id
  __shared__ int sdnew[512];  // new id -> degree
  __shared__ int sexcl[512];  // new id -> range begin
  __shared__ int ssc[512];
  __shared__ int scur[512];
  __shared__ int svc[NNODES];
  __shared__ int shist[64];
  __shared__ int shcur[64];
  int tid = threadIdx.x;
  int bx = blockIdx.x;

  if (bx == 0) {
    sdeg[tid] = 0;
    for (int n = tid; n < NNODES; n += 512) svc[n] = 0;
    if (tid < 64) { shist[tid] = 0; shcur[tid] = 0; }
    __syncthreads();
    for (int e = tid; e < E; e += 512) atomicAdd(&sdeg[cn[e]], 1);
    __syncthreads();
    int d = (tid < MM) ? sdeg[tid] : 0;
    if (tid < MM) atomicAdd(&shist[d], 1);
    __syncthreads();
    if (tid == 0) {
      int acc = 0;
      for (int i = 0; i < 64; ++i) { int h = shist[i]; shist[i] = acc; shcur[i] = acc; acc += h; }
    }
    __syncthreads();
    if (tid < MM) {
      int nid = atomicAdd(&shcur[d], 1);
      scinv[tid] = nid;
      cperm[nid] = tid;          // new -> orig (for parity-LLR lookup)
      sdnew[nid] = d;
    }
    __syncthreads();
    // scan (unpadded) lengths over NEW order
    int v = (tid < MM) ? sdnew[tid] : 0;
    ssc[tid] = v;
    __syncthreads();
    for (int o = 1; o < 512; o <<= 1) {
      int x = (tid >= o) ? ssc[tid - o] : 0;
      __syncthreads();
      ssc[tid] += x;
      __syncthreads();
    }
    int excl = ssc[tid] - v;
    sexcl[tid] = excl;
    scur[tid] = excl;
    if (tid < MM) {
      coff[tid]  = excl;
      cdend[tid] = excl + sdnew[tid] - 1;  // product loop: [beg, dend) = info edges
      if (tid == MM - 1) coff[MM] = ssc[tid];
    }
    __syncthreads();
    for (int e = tid; e < E; e += 512) {
      int c = cn[e], n = vn[e];
      int nc = scinv[c];
      int slot;
      if (n >= KK) {
        slot = sexcl[nc] + sdeg[c] - 1;    // parity edge -> last slot
      } else {
        slot = atomicAdd(&scur[nc], 1);    // info edges fill [beg, beg+d-1)
      }
      cinfo[slot] = (nc << 16) | n;
      if (n < KK) {
        int t = atomicAdd(&svc[n], 1);
        if (t < MAXVDEG) vlist[n * MAXVDEG + t] = slot;
      }
    }
    if (tid == 0) {
      double no = 1.0 / (pow(10.0, (double)ebno[0] * 0.1) * 2.0);  // BPS*RATE = 2
      nobuf[0] = no;
      nobuf[1] = sqrt(no * 0.5);
    }
    return;
  }

  if (bx <= packBlocks) {
    int id = (bx - 1) * 512 + tid;
    if (id < MM * 16) {
      int j = id >> 4, w = id & 15;
      unsigned word = 0u;
      int base = w * 32;
      for (int bit = 0; bit < 32; ++bit) {
        int i = base + bit;
        if (i < KK && P[i * MM + j] != 0) word |= (1u << bit);
      }
      Ppack[j * 16 + w] = word;
    } else {
      int id2 = id - MM * 16;
      if (id2 < ncw * 16) {
        int cw = id2 >> 4, w = id2 & 15;
        unsigned word = 0u;
        int base = w * 32;
        for (int bit = 0; bit < 32; ++bit) {
          int i = base + bit;
          if (i < KK && b[cw * KK + i] != 0) word |= (1u << bit);
        }
        bpack[cw * 16 + w] = word;
      }
    }
    return;
  }

  int id = (bx - 1 - packBlocks) * 512 + tid;
  if (id < ncw * KK) out[id] = (float)b[id];
}

// ---------------- 16-QAM constellation (fp32 TX symbol) --------------------
__device__ __forceinline__ void qam_pointf(int p, float& re, float& im) {
  const float s = 0.31622776601683794f;  // 1/sqrt(10)
  int b0 = (p >> 3) & 1, b1 = (p >> 2) & 1, b2 = (p >> 1) & 1, b3 = p & 1;
  re = (float)((1 - 2 * b0) * (2 - (1 - 2 * b2))) * s;
  im = (float)((1 - 2 * b1) * (2 - (1 - 2 * b3))) * s;
}

// ---------------- BP helpers ----------------
__device__ __forceinline__ float tanh_half(float m) {
  float mc = fminf(fmaxf(m, -19.8f), 19.8f);
  float e = __expf(mc);
  float t = 1.0f - __fdividef(2.0f, e + 1.0f);
  return (t >= 0.0f) ? fmaxf(t, 1e-7f) : fminf(t, -1e-7f);
}
__device__ __forceinline__ float pclip(float P, float t) {
  return copysignf(fminf(fabsf(P), 0.999999f * fabsf(t)), P);
}
__device__ __forceinline__ float tfloor(float t) {
  return (t >= 0.0f) ? fmaxf(t, 1e-7f) : fminf(t, -1e-7f);
}
__device__ __forceinline__ float atanh2c(float P, float t) {
  float r = __fdividef(P, t);
  r = fminf(fmaxf(r, -0.999999f), 0.999999f);
  return __logf(__fdividef(1.0f + r, 1.0f - r));
}

// per-column forward solve + max-log demap, column index J compile-time.
#define SOLVE_DEMAP(J, Lout) {                                                          \
  float u0r = Hr[0][J] * i00,               u0i = Hi[0][J] * i00;                       \
  float u1r = (Hr[1][J] - (L10r * u0r - L10i * u0i)) * i11;                             \
  float u1i = (Hi[1][J] - (L10r * u0i + L10i * u0r)) * i11;                             \
  float u2r = (Hr[2][J] - (L20r * u0r - L20i * u0i) - (L21r * u1r - L21i * u1i)) * i22; \
  float u2i = (Hi[2][J] - (L20r * u0i + L20i * u0r) - (L21r * u1i + L21i * u1r)) * i22; \
  float u3r = (Hr[3][J] - (L30r * u0r - L30i * u0i) - (L31r * u1r - L31i * u1i)         \
                        - (L32r * u2r - L32i * u2i)) * i33;                             \
  float u3i = (Hi[3][J] - (L30r * u0i + L30i * u0r) - (L31r * u1i + L31i * u1r)         \
                        - (L32r * u2i + L32i * u2r)) * i33;                             \
  float dj = (u0r * u0r + u0i * u0i) + (u1r * u1r + u1i * u1i)                          \
           + (u2r * u2r + u2i * u2i) + (u3r * u3r + u3i * u3i);                         \
  float rr = (u0r * yr[0] + u0i * yi[0]) + (u1r * yr[1] + u1i * yi[1])                  \
           + (u2r * yr[2] + u2i * yi[2]) + (u3r * yr[3] + u3i * yi[3]);                 \
  float ri = (u0r * yi[0] - u0i * yr[0]) + (u1r * yi[1] - u1i * yr[1])                  \
           + (u2r * yi[2] - u2i * yr[2]) + (u3r * yi[3] - u3i * yr[3]);                 \
  float rdj = __fdividef(1.0f, dj);                                                    \
  float xhr = rr * rdj, xhi = ri * rdj;                                                \
  float gap = 1.0f - dj;                                                               \
  float inoe = __fdividef(dj, fmaxf(gap, dj * 1e-12f));                                \
  float m0[4] = {-1e30f, -1e30f, -1e30f, -1e30f};                                      \
  float m1[4] = {-1e30f, -1e30f, -1e30f, -1e30f};                                      \
  _Pragma("unroll")                                                                    \
  for (int p = 0; p < 16; ++p) {                                                       \
    float dr = xhr - PRT[p], di = xhi - PIT[p];                                        \
    float met = -(dr * dr + di * di) * inoe;                                           \
    _Pragma("unroll")                                                                  \
    for (int k = 0; k < 4; ++k) {                                                      \
      if ((p >> (3 - k)) & 1) m1[k] = fmaxf(m1[k], met);                               \
      else                    m0[k] = fmaxf(m0[k], met);                               \
    }                                                                                  \
  }                                                                                    \
  _Pragma("unroll")                                                                    \
  for (int k = 0; k < 4; ++k) Lout[k] = m0[k] - m1[k];                                 \
}

// ---------------- fused LMMSE + BP, one block per (bt, plane) --------------
// sL aliases sT[0..NNODES).  LDS total = 16 + 4 KB = 20 KB -> 8 blocks/CU
// (100% wave cap; grid supplies ~7.8 blocks/CU).
__global__ void __launch_bounds__(256, 8)
k_fused(const float* __restrict__ h_re, const float* __restrict__ h_im,
        const float* __restrict__ n_re, const float* __restrict__ n_im,
        const double* __restrict__ nobuf,
        const unsigned* __restrict__ bpack, const unsigned* __restrict__ Ppack,
        const int* __restrict__ vlist, const int* __restrict__ coff,
        const int* __restrict__ cdend, const int* __restrict__ cperm,
        const int* __restrict__ cinfo, float* __restrict__ out, int ncw) {
  __shared__ float2 sT[EMAX];    // tanh(v2c/2) per edge slot, SWZ-indexed (16 KB)
  __shared__ float2 sP[512];     // per-check product of tanh (4 KB)
  float2* sL = sT;               // staged LLRs alias (first NNODES entries, raw-indexed)

  int tid = threadIdx.x;
  int pairId = blockIdx.x;       // = bt*2 + plane
  int bt = pairId >> 1, plane = pairId & 1;

  // ================= phase 1: LMMSE for this block's 250 symbols ===========
  if (tid < NSYM) {
    int t = bt * NSYM + tid;
    int s = tid;

    float no = (float)nobuf[0];
    float sq = (float)nobuf[1];
    const float is2 = 0.70710678118654752f;  // 1/sqrt(2)

    float Hr[4][4], Hi[4][4];
    {
      const float4* hr4 = (const float4*)h_re;
      const float4* hi4 = (const float4*)h_im;
      #pragma unroll
      for (int i = 0; i < 4; ++i) {
        float4 a = hr4[t * 4 + i], c = hi4[t * 4 + i];
        Hr[i][0] = a.x * is2; Hr[i][1] = a.y * is2;
        Hr[i][2] = a.z * is2; Hr[i][3] = a.w * is2;
        Hi[i][0] = c.x * is2; Hi[i][1] = c.y * is2;
        Hi[i][2] = c.z * is2; Hi[i][3] = c.w * is2;
      }
    }

    // transmitted symbols: encode+map inline
    float xr[4], xi[4];
    #pragma unroll
    for (int ue = 0; ue < 4; ++ue) {
      const unsigned* bp = bpack + (bt * 4 + ue) * 16;
      int v = 0;
      #pragma unroll
      for (int k = 0; k < 4; ++k) {
        int n = 4 * s + k;
        int bit;
        if (n < KK) {
          bit = (bp[n >> 5] >> (n & 31)) & 1;
        } else {
          const unsigned* pp = Ppack + (n - KK) * 16;
          int cnt = 0;
          #pragma unroll
          for (int w = 0; w < 16; ++w) cnt += __popc(bp[w] & pp[w]);
          bit = cnt & 1;
        }
        v = (v << 1) | bit;  // MSB-first: weights 8,4,2,1
      }
      qam_pointf(v, xr[ue], xi[ue]);
    }

    // y = H x + w
    float yr[4], yi[4];
    {
      float4 wr = ((const float4*)n_re)[t];
      float4 wi = ((const float4*)n_im)[t];
      float wrv[4] = {wr.x, wr.y, wr.z, wr.w};
      float wiv[4] = {wi.x, wi.y, wi.z, wi.w};
      #pragma unroll
      for (int i = 0; i < 4; ++i) {
        float ar = wrv[i] * sq;
        float ai = wiv[i] * sq;
        #pragma unroll
        for (int j = 0; j < 4; ++j) {
          ar += Hr[i][j] * xr[j] - Hi[i][j] * xi[j];
          ai += Hr[i][j] * xi[j] + Hi[i][j] * xr[j];
        }
        yr[i] = ar; yi[i] = ai;
      }
    }

    // A = H H^H + no I, lower triangle, into scalars
    auto dotc = [&](int i, int j, float& ar, float& ai) {
      float r = 0.0f, m = 0.0f;
      #pragma unroll
      for (int k = 0; k < 4; ++k) {
        r += Hr[i][k] * Hr[j][k] + Hi[i][k] * Hi[j][k];
        m += Hi[i][k] * Hr[j][k] - Hr[i][k] * Hi[j][k];
      }
      ar = r; ai = m;
    };
    float a00, a11, a22, a33, dum;
    float a10r, a10i, a20r, a20i, a21r, a21i, a30r, a30i, a31r, a31i, a32r, a32i;
    dotc(0, 0, a00, dum);  a00 += no;
    dotc(1, 0, a10r, a10i);
    dotc(1, 1, a11, dum);  a11 += no;
    dotc(2, 0, a20r, a20i);
    dotc(2, 1, a21r, a21i);
    dotc(2, 2, a22, dum);  a22 += no;
    dotc(3, 0, a30r, a30i);
    dotc(3, 1, a31r, a31i);
    dotc(3, 2, a32r, a32i);
    dotc(3, 3, a33, dum);  a33 += no;

    // Cholesky in inverse-diagonal form
    float i00 = rsqrtf(a00);
    float L10r = a10r * i00, L10i = a10i * i00;
    float L20r = a20r * i00, L20i = a20i * i00;
    float L30r = a30r * i00, L30i = a30i * i00;
    float d11 = a11 - (L10r * L10r + L10i * L10i);
    float i11 = rsqrtf(d11);
    float L21r = (a21r - (L20r * L10r + L20i * L10i)) * i11;
    float L21i = (a21i - (L20i * L10r - L20r * L10i)) * i11;
    float L31r = (a31r - (L30r * L10r + L30i * L10i)) * i11;
    float L31i = (a31i - (L30i * L10r - L30r * L10i)) * i11;
    float d22 = a22 - (L20r * L20r + L20i * L20i) - (L21r * L21r + L21i * L21i);
    float i22 = rsqrtf(d22);
    float L32r = (a32r - (L30r * L20r + L30i * L20i) - (L31r * L21r + L31i * L21i)) * i22;
    float L32i = (a32i - (L30i * L20r - L30r * L20i) - (L31i * L21r - L31r * L21i)) * i22;
    float d33 = a33 - (L30r * L30r + L30i * L30i) - (L31r * L31r + L31i * L31i)
                    - (L32r * L32r + L32i * L32i);
    float i33 = rsqrtf(d33);

    // forward solve on y only: v = L^{-1} y (in place)
    {
      float v0r = yr[0] * i00,               v0i = yi[0] * i00;
      float v1r = (yr[1] - (L10r * v0r - L10i * v0i)) * i11;
      float v1i = (yi[1] - (L10r * v0i + L10i * v0r)) * i11;
      float v2r = (yr[2] - (L20r * v0r - L20i * v0i) - (L21r * v1r - L21i * v1i)) * i22;
      float v2i = (yi[2] - (L20r * v0i + L20i * v0r) - (L21r * v1i + L21i * v1r)) * i22;
      float v3r = (yr[3] - (L30r * v0r - L30i * v0i) - (L31r * v1r - L31i * v1i)
                         - (L32r * v2r - L32i * v2i)) * i33;
      float v3i = (yi[3] - (L30r * v0i + L30i * v0r) - (L31r * v1i + L31i * v1r)
                         - (L32r * v2i + L32i * v2r)) * i33;
      yr[0] = v0r; yi[0] = v0i; yr[1] = v1r; yi[1] = v1i;
      yr[2] = v2r; yi[2] = v2i; yr[3] = v3r; yi[3] = v3i;
    }

    // fp32 16-QAM table
    const float PRT[16] = { 0.31622776601683794f, 0.31622776601683794f, 0.9486832980505138f, 0.9486832980505138f,
                            0.31622776601683794f, 0.31622776601683794f, 0.9486832980505138f, 0.9486832980505138f,
                           -0.31622776601683794f,-0.31622776601683794f,-0.9486832980505138f,-0.9486832980505138f,
                           -0.31622776601683794f,-0.31622776601683794f,-0.9486832980505138f,-0.9486832980505138f };
    const float PIT[16] = { 0.31622776601683794f, 0.9486832980505138f, 0.31622776601683794f, 0.9486832980505138f,
                           -0.31622776601683794f,-0.9486832980505138f,-0.31622776601683794f,-0.9486832980505138f,
                            0.31622776601683794f, 0.9486832980505138f, 0.31622776601683794f, 0.9486832980505138f,
                           -0.31622776601683794f,-0.9486832980505138f,-0.31622776601683794f,-0.9486832980505138f };

    // only this plane's 2 UE columns (uniform branch per block)
    float lA[4], lB[4];
    if (plane == 0) {
      SOLVE_DEMAP(0, lA);
      SOLVE_DEMAP(1, lB);
    } else {
      SOLVE_DEMAP(2, lA);
      SOLVE_DEMAP(3, lB);
    }
    #pragma unroll
    for (int k = 0; k < 4; ++k) {
      sL[4 * s + k] = make_float2(lA[k], lB[k]);
    }
  }
  __syncthreads();

  // ================= phase 2: LDS-resident BP (2 codewords) ===============
  // own info-node state in registers
  float2 Ln[2], En[2];
  int pk0[2], pk1[2], pk2[2]; bool iok[2];
  #pragma unroll
  for (int i = 0; i < 2; ++i) {
    int n = tid + TB * i;
    iok[i] = n < KK;
    Ln[i] = make_float2(0.f, 0.f);
    En[i] = make_float2(1.f, 1.f);
    pk0[i] = pk1[i] = pk2[i] = 0;
    if (iok[i]) {
      float2 L = sL[n];
      Ln[i] = L;
      En[i] = make_float2(__expf(fminf(fmaxf(L.x, -55.f), 55.f)),
                          __expf(fminf(fmaxf(L.y, -55.f), 55.f)));
      int s0 = vlist[n * MAXVDEG], s1 = vlist[n * MAXVDEG + 1], s2 = vlist[n * MAXVDEG + 2];
      pk0[i] = (cinfo[s0] & 0xffff0000) | SWZ(s0);
      pk1[i] = (cinfo[s1] & 0xffff0000) | SWZ(s1);
      pk2[i] = (cinfo[s2] & 0xffff0000) | SWZ(s2);
    }
  }
  // per-check constant: tanh of the parity-node LLR.  Check tid (new id)
  // corresponds to ORIGINAL check cperm[tid]; its parity var is KK+orig.
  float2 qpar0, qpar1;
  {
    int oc0 = cperm[tid];
    float2 Lp0 = sL[KK + oc0];
    qpar0 = make_float2(tanh_half(Lp0.x), tanh_half(Lp0.y));
  }
  bool c1ok = (tid + TB) < MM;
  if (c1ok) {
    int oc1 = cperm[tid + TB];
    float2 Lp1 = sL[KK + oc1];
    qpar1 = make_float2(tanh_half(Lp1.x), tanh_half(Lp1.y));
  } else {
    qpar1 = make_float2(1.f, 1.f);
  }
  int beg0 = coff[tid],                  dnd0 = cdend[tid];
  int beg1 = c1ok ? coff[tid + TB]  : 0, dnd1 = c1ok ? cdend[tid + TB] : 0;
  __syncthreads();  // sL (= sT[0..1000)) reads done; sT writes may now begin

  for (int it = 0; it < NITERS; ++it) {
    // ---- pass 1: info-node var update ----
    if (it == 0) {
      #pragma unroll
      for (int i = 0; i < 2; ++i) {
        if (iok[i]) {
          float2 t = make_float2(tanh_half(Ln[i].x), tanh_half(Ln[i].y));
          sT[pk0[i] & 0xffff] = t;
          sT[pk1[i] & 0xffff] = t;
          sT[pk2[i] & 0xffff] = t;
        }
      }
    } else {
      #pragma unroll
      for (int i = 0; i < 2; ++i) {
        if (iok[i]) {
          int s0 = pk0[i] & 0xffff, c0 = ((unsigned)pk0[i]) >> 16;
          int s1 = pk1[i] & 0xffff, c1 = ((unsigned)pk1[i]) >> 16;
          int s2 = pk2[i] & 0xffff, c2 = ((unsigned)pk2[i]) >> 16;
          float2 P0 = sP[c0], P1 = sP[c1], P2 = sP[c2];
          float2 t0 = sT[s0], t1 = sT[s1], t2 = sT[s2];
          // lane x
          float p0 = pclip(P0.x, t0.x), p1 = pclip(P1.x, t1.x), p2 = pclip(P2.x, t2.x);
          float a0 = t0.x + p0, a1 = t1.x + p1, a2 = t2.x + p2;
          float b0 = t0.x - p0, b1 = t1.x - p1, b2 = t2.x - p2;
          float Ex = En[i].x;
          float A0 = Ex * (a1 * a2), A1 = Ex * (a0 * a2), A2 = Ex * (a0 * a1);
          float B0 = b1 * b2,        B1 = b0 * b2,        B2 = b0 * b1;
          float n0x = tfloor(__fdividef(A0 - B0, A0 + B0));
          float n1x = tfloor(__fdividef(A1 - B1, A1 + B1));
          float n2x = tfloor(__fdividef(A2 - B2, A2 + B2));
          // lane y
          float q0 = pclip(P0.y, t0.y), q1 = pclip(P1.y, t1.y), q2 = pclip(P2.y, t2.y);
          float c0a = t0.y + q0, c1a = t1.y + q1, c2a = t2.y + q2;
          float d0b = t0.y - q0, d1b = t1.y - q1, d2b = t2.y - q2;
          float Ey = En[i].y;
          float C0 = Ey * (c1a * c2a), C1 = Ey * (c0a * c2a), C2 = Ey * (c0a * c1a);
          float D0 = d1b * d2b,        D1 = d0b * d2b,        D2 = d0b * d1b;
          float n0y = tfloor(__fdividef(C0 - D0, C0 + D0));
          float n1y = tfloor(__fdividef(C1 - D1, C1 + D1));
          float n2y = tfloor(__fdividef(C2 - D2, C2 + D2));
          sT[s0] = make_float2(n0x, n0y);
          sT[s1] = make_float2(n1x, n1y);
          sT[s2] = make_float2(n2x, n2y);
        }
      }
    }
    __syncthreads();
    // ---- pass 2: per-check products (parity factor from register) ----
    // Sorted checks: uniform trip counts per wave; SWZ spreads the
    // power-of-2 slot strides across bank pairs.
    {
      float px = qpar0.x, py = qpar0.y;
      for (int e = beg0; e < dnd0; ++e) { float2 tt = sT[SWZ(e)]; px *= tt.x; py *= tt.y; }
      sP[tid] = make_float2(px, py);
      if (c1ok) {
        float qx = qpar1.x, qy = qpar1.y;
        for (int e = beg1; e < dnd1; ++e) { float2 tt = sT[SWZ(e)]; qx *= tt.x; qy *= tt.y; }
        sP[tid + TB] = make_float2(qx, qy);
      }
    }
    __syncthreads();
  }

  // ---- decide: additive log form (once) ----
  int cw0 = pairId * 2;
  float* o0 = out + (size_t)ncw * KK + (size_t)cw0 * KK;
  float* o1 = o0 + KK;
  #pragma unroll
  for (int i = 0; i < 2; ++i) {
    if (iok[i]) {
      int n = tid + TB * i;
      int s0 = pk0[i] & 0xffff, c0 = ((unsigned)pk0[i]) >> 16;
      int s1 = pk1[i] & 0xffff, c1 = ((unsigned)pk1[i]) >> 16;
      int s2 = pk2[i] & 0xffff, c2 = ((unsigned)pk2[i]) >> 16;
      float2 P0 = sP[c0], P1 = sP[c1], P2 = sP[c2];
      float2 t0 = sT[s0], t1 = sT[s1], t2 = sT[s2];
      float2 L = Ln[i];
      float ax = L.x + atanh2c(P0.x, t0.x) + atanh2c(P1.x, t1.x) + atanh2c(P2.x, t2.x);
      float ay = L.y + atanh2c(P0.y, t0.y) + atanh2c(P1.y, t1.y) + atanh2c(P2.y, t2.y);
      o0[n] = (ax < 0.0f) ? 1.0f : 0.0f;
      o1[n] = (ay < 0.0f) ? 1.0f : 0.0f;
    }
  }
}

// ---------------- launcher ----------------
extern "C" void kernel_launch(void* const* d_in, const int* in_sizes, int n_in,
                              void* d_out, int out_size, void* d_ws, size_t ws_size,
                              hipStream_t stream) {
  const float* ebno = (const float*)d_in[1];
  const int*   b    = (const int*)d_in[2];
  const int*   P    = (const int*)d_in[3];
  const int*   cn   = (const int*)d_in[4];
  const int*   vn   = (const int*)d_in[5];
  const float* h_re = (const float*)d_in[6];
  const float* h_im = (const float*)d_in[7];
  const float* nre  = (const float*)d_in[8];
  const float* nim  = (const float*)d_in[9];
  float* out = (float*)d_out;

  int E     = in_sizes[4];
  int batch = in_sizes[2] / (4 * KK);
  int ncw   = batch * 4;

  char* ws = (char*)d_ws;
  size_t off = 0;
  auto alloc = [&](size_t bytes) -> void* {
    void* p = ws + off;
    off += (bytes + 255) & ~(size_t)255;
    return p;
  };
  unsigned* Ppack  = (unsigned*)alloc((size_t)MM * 16 * 4);
  unsigned* bpack  = (unsigned*)alloc((size_t)ncw * 16 * 4);
  int*      coff   = (int*)alloc((size_t)(MM + 1) * 4);
  int*      cdend  = (int*)alloc((size_t)MM * 4);
  int*      cperm  = (int*)alloc((size_t)MM * 4);
  int*      cinfo  = (int*)alloc((size_t)EMAX * 4);
  int*      vlist  = (int*)alloc((size_t)NNODES * MAXVDEG * 4);
  double*   nobuf  = (double*)alloc(2 * 8);
  (void)ws_size; (void)n_in; (void)out_size;

  int packItems  = MM * 16 + ncw * 16;
  int packBlocks = (packItems + 511) / 512;
  int bfBlocks   = (ncw * KK + 511) / 512;
  int setupGrid  = 1 + packBlocks + bfBlocks;

  k_setup<<<dim3(setupGrid), dim3(512), 0, stream>>>(cn, vn, E, ebno, P, b, ncw,
                                                     cinfo, vlist, coff, cdend, cperm,
                                                     nobuf, Ppack, bpack, out, packBlocks);
  k_fused<<<dim3(ncw / 2), dim3(256), 0, stream>>>(h_re, h_im, nre, nim, nobuf,
                                                   bpack, Ppack, vlist, coff, cdend,
                                                   cperm, cinfo, out, ncw);
}

// Round 5
// 176.782 us; speedup vs baseline: 1.5068x; 1.5068x over previous
//
#include <hip/hip_runtime.h>
#include <math.h>

// Problem constants (from reference)
#define KK     500   // info bits
#define MM     500   // parity checks
#define NNODES 1000  // N = K + M variable nodes
#define NSYM   250   // N / BPS
#define NITERS 5
#define MAXVDEG 4    // info vars degree exactly 3 (row weight of P), parity vars 1
#define EMAX   2048  // E = 2000 slots (unpadded), round up
#define TB     256

// XOR bank swizzle on sT indices: involution, bijective on [0,2048).
#define SWZ(s) ((s) ^ (((s) >> 4) & 3))

// ---------------- setup: graph build + bit packing + bf output -------------
// Checks COUNTING-SORTED by total degree and relabeled (new id = rank):
// waves in BP pass-2 get uniform trip counts (no divergence).  Unpadded
// layout (20 KB LDS in k_fused -> 8 blocks/CU); bank spread via SWZ.
__global__ void __launch_bounds__(512)
k_setup(const int* __restrict__ cn, const int* __restrict__ vn, int E,
        const float* __restrict__ ebno, const int* __restrict__ P,
        const int* __restrict__ b, int ncw,
        int* __restrict__ cinfo, int* __restrict__ vlist, int* __restrict__ coff,
        int* __restrict__ cdend, int* __restrict__ cperm,
        double* __restrict__ nobuf, unsigned* __restrict__ Ppack,
        unsigned* __restrict__ bpack, float* __restrict__ out, int packBlocks) {
  __shared__ int sdeg[512];   // orig check -> total degree
  __shared__ int scinv[512];  // orig check -> new id
  __shared__ int sdnew[512];  // new id -> degree
  __shared__ int sexcl[512];  // new id -> range begin
  __shared__ int ssc[512];
  __shared__ int scur[512];
  __shared__ int svc[NNODES];
  __shared__ int shist[64];
  __shared__ int shcur[64];
  int tid = threadIdx.x;
  int bx = blockIdx.x;

  if (bx == 0) {
    sdeg[tid] = 0;
    for (int n = tid; n < NNODES; n += 512) svc[n] = 0;
    if (tid < 64) { shist[tid] = 0; shcur[tid] = 0; }
    __syncthreads();
    for (int e = tid; e < E; e += 512) atomicAdd(&sdeg[cn[e]], 1);
    __syncthreads();
    int d = (tid < MM) ? sdeg[tid] : 0;
    if (tid < MM) atomicAdd(&shist[d], 1);
    __syncthreads();
    if (tid == 0) {
      int acc = 0;
      for (int i = 0; i < 64; ++i) { int h = shist[i]; shist[i] = acc; shcur[i] = acc; acc += h; }
    }
    __syncthreads();
    if (tid < MM) {
      int nid = atomicAdd(&shcur[d], 1);
      scinv[tid] = nid;
      cperm[nid] = tid;          // new -> orig (for parity-LLR lookup)
      sdnew[nid] = d;
    }
    __syncthreads();
    // scan (unpadded) lengths over NEW order
    int v = (tid < MM) ? sdnew[tid] : 0;
    ssc[tid] = v;
    __syncthreads();
    for (int o = 1; o < 512; o <<= 1) {
      int x = (tid >= o) ? ssc[tid - o] : 0;
      __syncthreads();
      ssc[tid] += x;
      __syncthreads();
    }
    int excl = ssc[tid] - v;
    sexcl[tid] = excl;
    scur[tid] = excl;
    if (tid < MM) {
      coff[tid]  = excl;
      cdend[tid] = excl + sdnew[tid] - 1;  // product loop: [beg, dend) = info edges
      if (tid == MM - 1) coff[MM] = ssc[tid];
    }
    __syncthreads();
    for (int e = tid; e < E; e += 512) {
      int c = cn[e], n = vn[e];
      int nc = scinv[c];
      int slot;
      if (n >= KK) {
        slot = sexcl[nc] + sdeg[c] - 1;    // parity edge -> last slot
      } else {
        slot = atomicAdd(&scur[nc], 1);    // info edges fill [beg, beg+d-1)
      }
      cinfo[slot] = (nc << 16) | n;
      if (n < KK) {
        int t = atomicAdd(&svc[n], 1);
        if (t < MAXVDEG) vlist[n * MAXVDEG + t] = slot;
      }
    }
    if (tid == 0) {
      double no = 1.0 / (pow(10.0, (double)ebno[0] * 0.1) * 2.0);  // BPS*RATE = 2
      nobuf[0] = no;
      nobuf[1] = sqrt(no * 0.5);
    }
    return;
  }

  if (bx <= packBlocks) {
    int id = (bx - 1) * 512 + tid;
    if (id < MM * 16) {
      int j = id >> 4, w = id & 15;
      unsigned word = 0u;
      int base = w * 32;
      for (int bit = 0; bit < 32; ++bit) {
        int i = base + bit;
        if (i < KK && P[i * MM + j] != 0) word |= (1u << bit);
      }
      Ppack[j * 16 + w] = word;
    } else {
      int id2 = id - MM * 16;
      if (id2 < ncw * 16) {
        int cw = id2 >> 4, w = id2 & 15;
        unsigned word = 0u;
        int base = w * 32;
        for (int bit = 0; bit < 32; ++bit) {
          int i = base + bit;
          if (i < KK && b[cw * KK + i] != 0) word |= (1u << bit);
        }
        bpack[cw * 16 + w] = word;
      }
    }
    return;
  }

  int id = (bx - 1 - packBlocks) * 512 + tid;
  if (id < ncw * KK) out[id] = (float)b[id];
}

// ---------------- 16-QAM constellation (fp32 TX symbol) --------------------
__device__ __forceinline__ void qam_pointf(int p, float& re, float& im) {
  const float s = 0.31622776601683794f;  // 1/sqrt(10)
  int b0 = (p >> 3) & 1, b1 = (p >> 2) & 1, b2 = (p >> 1) & 1, b3 = p & 1;
  re = (float)((1 - 2 * b0) * (2 - (1 - 2 * b2))) * s;
  im = (float)((1 - 2 * b1) * (2 - (1 - 2 * b3))) * s;
}

// ---------------- BP helpers ----------------
__device__ __forceinline__ float tanh_half(float m) {
  float mc = fminf(fmaxf(m, -19.8f), 19.8f);
  float e = __expf(mc);
  float t = 1.0f - __fdividef(2.0f, e + 1.0f);
  return (t >= 0.0f) ? fmaxf(t, 1e-7f) : fminf(t, -1e-7f);
}
__device__ __forceinline__ float pclip(float P, float t) {
  return copysignf(fminf(fabsf(P), 0.999999f * fabsf(t)), P);
}
__device__ __forceinline__ float tfloor(float t) {
  return (t >= 0.0f) ? fmaxf(t, 1e-7f) : fminf(t, -1e-7f);
}
__device__ __forceinline__ float atanh2c(float P, float t) {
  float r = __fdividef(P, t);
  r = fminf(fmaxf(r, -0.999999f), 0.999999f);
  return __logf(__fdividef(1.0f + r, 1.0f - r));
}

// per-column forward solve + max-log demap, column index J compile-time.
#define SOLVE_DEMAP(J, Lout) {                                                          \
  float u0r = Hr[0][J] * i00,               u0i = Hi[0][J] * i00;                       \
  float u1r = (Hr[1][J] - (L10r * u0r - L10i * u0i)) * i11;                             \
  float u1i = (Hi[1][J] - (L10r * u0i + L10i * u0r)) * i11;                             \
  float u2r = (Hr[2][J] - (L20r * u0r - L20i * u0i) - (L21r * u1r - L21i * u1i)) * i22; \
  float u2i = (Hi[2][J] - (L20r * u0i + L20i * u0r) - (L21r * u1i + L21i * u1r)) * i22; \
  float u3r = (Hr[3][J] - (L30r * u0r - L30i * u0i) - (L31r * u1r - L31i * u1i)         \
                        - (L32r * u2r - L32i * u2i)) * i33;                             \
  float u3i = (Hi[3][J] - (L30r * u0i + L30i * u0r) - (L31r * u1i + L31i * u1r)         \
                        - (L32r * u2i + L32i * u2r)) * i33;                             \
  float dj = (u0r * u0r + u0i * u0i) + (u1r * u1r + u1i * u1i)                          \
           + (u2r * u2r + u2i * u2i) + (u3r * u3r + u3i * u3i);                         \
  float rr = (u0r * yr[0] + u0i * yi[0]) + (u1r * yr[1] + u1i * yi[1])                  \
           + (u2r * yr[2] + u2i * yi[2]) + (u3r * yr[3] + u3i * yi[3]);                 \
  float ri = (u0r * yi[0] - u0i * yr[0]) + (u1r * yi[1] - u1i * yr[1])                  \
           + (u2r * yi[2] - u2i * yr[2]) + (u3r * yi[3] - u3i * yr[3]);                 \
  float rdj = __fdividef(1.0f, dj);                                                    \
  float xhr = rr * rdj, xhi = ri * rdj;                                                \
  float gap = 1.0f - dj;                                                               \
  float inoe = __fdividef(dj, fmaxf(gap, dj * 1e-12f));                                \
  float m0[4] = {-1e30f, -1e30f, -1e30f, -1e30f};                                      \
  float m1[4] = {-1e30f, -1e30f, -1e30f, -1e30f};                                      \
  _Pragma("unroll")                                                                    \
  for (int p = 0; p < 16; ++p) {                                                       \
    float dr = xhr - PRT[p], di = xhi - PIT[p];                                        \
    float met = -(dr * dr + di * di) * inoe;                                           \
    _Pragma("unroll")                                                                  \
    for (int k = 0; k < 4; ++k) {                                                      \
      if ((p >> (3 - k)) & 1) m1[k] = fmaxf(m1[k], met);                               \
      else                    m0[k] = fmaxf(m0[k], met);                               \
    }                                                                                  \
  }                                                                                    \
  _Pragma("unroll")                                                                    \
  for (int k = 0; k < 4; ++k) Lout[k] = m0[k] - m1[k];                                 \
}

// ---------------- fused LMMSE + BP, one block per (bt, plane) --------------
// sL aliases sT[0..NNODES).  LDS total = 16 + 4 KB = 20 KB.
// __launch_bounds__(256, 4): min-waves floor 4 keeps the allocator at the
// natural ~48 VGPR (round-16 lesson: floor 8 forced 32 VGPR + full spill of
// the phase-1 matrices -> 205 MB scratch writes, 2x regression).  48 VGPR
// <= 64 means 8 waves/SIMD (= 8 blocks/CU at 20 KB LDS) is still reachable
// at RUNTIME -- the floor only constrains the allocator, not occupancy.
__global__ void __launch_bounds__(256, 4)
k_fused(const float* __restrict__ h_re, const float* __restrict__ h_im,
        const float* __restrict__ n_re, const float* __restrict__ n_im,
        const double* __restrict__ nobuf,
        const unsigned* __restrict__ bpack, const unsigned* __restrict__ Ppack,
        const int* __restrict__ vlist, const int* __restrict__ coff,
        const int* __restrict__ cdend, const int* __restrict__ cperm,
        const int* __restrict__ cinfo, float* __restrict__ out, int ncw) {
  __shared__ float2 sT[EMAX];    // tanh(v2c/2) per edge slot, SWZ-indexed (16 KB)
  __shared__ float2 sP[512];     // per-check product of tanh (4 KB)
  float2* sL = sT;               // staged LLRs alias (first NNODES entries, raw-indexed)

  int tid = threadIdx.x;
  int pairId = blockIdx.x;       // = bt*2 + plane
  int bt = pairId >> 1, plane = pairId & 1;

  // ================= phase 1: LMMSE for this block's 250 symbols ===========
  if (tid < NSYM) {
    int t = bt * NSYM + tid;
    int s = tid;

    float no = (float)nobuf[0];
    float sq = (float)nobuf[1];
    const float is2 = 0.70710678118654752f;  // 1/sqrt(2)

    float Hr[4][4], Hi[4][4];
    {
      const float4* hr4 = (const float4*)h_re;
      const float4* hi4 = (const float4*)h_im;
      #pragma unroll
      for (int i = 0; i < 4; ++i) {
        float4 a = hr4[t * 4 + i], c = hi4[t * 4 + i];
        Hr[i][0] = a.x * is2; Hr[i][1] = a.y * is2;
        Hr[i][2] = a.z * is2; Hr[i][3] = a.w * is2;
        Hi[i][0] = c.x * is2; Hi[i][1] = c.y * is2;
        Hi[i][2] = c.z * is2; Hi[i][3] = c.w * is2;
      }
    }

    // transmitted symbols: encode+map inline
    float xr[4], xi[4];
    #pragma unroll
    for (int ue = 0; ue < 4; ++ue) {
      const unsigned* bp = bpack + (bt * 4 + ue) * 16;
      int v = 0;
      #pragma unroll
      for (int k = 0; k < 4; ++k) {
        int n = 4 * s + k;
        int bit;
        if (n < KK) {
          bit = (bp[n >> 5] >> (n & 31)) & 1;
        } else {
          const unsigned* pp = Ppack + (n - KK) * 16;
          int cnt = 0;
          #pragma unroll
          for (int w = 0; w < 16; ++w) cnt += __popc(bp[w] & pp[w]);
          bit = cnt & 1;
        }
        v = (v << 1) | bit;  // MSB-first: weights 8,4,2,1
      }
      qam_pointf(v, xr[ue], xi[ue]);
    }

    // y = H x + w
    float yr[4], yi[4];
    {
      float4 wr = ((const float4*)n_re)[t];
      float4 wi = ((const float4*)n_im)[t];
      float wrv[4] = {wr.x, wr.y, wr.z, wr.w};
      float wiv[4] = {wi.x, wi.y, wi.z, wi.w};
      #pragma unroll
      for (int i = 0; i < 4; ++i) {
        float ar = wrv[i] * sq;
        float ai = wiv[i] * sq;
        #pragma unroll
        for (int j = 0; j < 4; ++j) {
          ar += Hr[i][j] * xr[j] - Hi[i][j] * xi[j];
          ai += Hr[i][j] * xi[j] + Hi[i][j] * xr[j];
        }
        yr[i] = ar; yi[i] = ai;
      }
    }

    // A = H H^H + no I, lower triangle, into scalars
    auto dotc = [&](int i, int j, float& ar, float& ai) {
      float r = 0.0f, m = 0.0f;
      #pragma unroll
      for (int k = 0; k < 4; ++k) {
        r += Hr[i][k] * Hr[j][k] + Hi[i][k] * Hi[j][k];
        m += Hi[i][k] * Hr[j][k] - Hr[i][k] * Hi[j][k];
      }
      ar = r; ai = m;
    };
    float a00, a11, a22, a33, dum;
    float a10r, a10i, a20r, a20i, a21r, a21i, a30r, a30i, a31r, a31i, a32r, a32i;
    dotc(0, 0, a00, dum);  a00 += no;
    dotc(1, 0, a10r, a10i);
    dotc(1, 1, a11, dum);  a11 += no;
    dotc(2, 0, a20r, a20i);
    dotc(2, 1, a21r, a21i);
    dotc(2, 2, a22, dum);  a22 += no;
    dotc(3, 0, a30r, a30i);
    dotc(3, 1, a31r, a31i);
    dotc(3, 2, a32r, a32i);
    dotc(3, 3, a33, dum);  a33 += no;

    // Cholesky in inverse-diagonal form
    float i00 = rsqrtf(a00);
    float L10r = a10r * i00, L10i = a10i * i00;
    float L20r = a20r * i00, L20i = a20i * i00;
    float L30r = a30r * i00, L30i = a30i * i00;
    float d11 = a11 - (L10r * L10r + L10i * L10i);
    float i11 = rsqrtf(d11);
    float L21r = (a21r - (L20r * L10r + L20i * L10i)) * i11;
    float L21i = (a21i - (L20i * L10r - L20r * L10i)) * i11;
    float L31r = (a31r - (L30r * L10r + L30i * L10i)) * i11;
    float L31i = (a31i - (L30i * L10r - L30r * L10i)) * i11;
    float d22 = a22 - (L20r * L20r + L20i * L20i) - (L21r * L21r + L21i * L21i);
    float i22 = rsqrtf(d22);
    float L32r = (a32r - (L30r * L20r + L30i * L20i) - (L31r * L21r + L31i * L21i)) * i22;
    float L32i = (a32i - (L30i * L20r - L30r * L20i) - (L31i * L21r - L31r * L21i)) * i22;
    float d33 = a33 - (L30r * L30r + L30i * L30i) - (L31r * L31r + L31i * L31i)
                    - (L32r * L32r + L32i * L32i);
    float i33 = rsqrtf(d33);

    // forward solve on y only: v = L^{-1} y (in place)
    {
      float v0r = yr[0] * i00,               v0i = yi[0] * i00;
      float v1r = (yr[1] - (L10r * v0r - L10i * v0i)) * i11;
      float v1i = (yi[1] - (L10r * v0i + L10i * v0r)) * i11;
      float v2r = (yr[2] - (L20r * v0r - L20i * v0i) - (L21r * v1r - L21i * v1i)) * i22;
      float v2i = (yi[2] - (L20r * v0i + L20i * v0r) - (L21r * v1i + L21i * v1r)) * i22;
      float v3r = (yr[3] - (L30r * v0r - L30i * v0i) - (L31r * v1r - L31i * v1i)
                         - (L32r * v2r - L32i * v2i)) * i33;
      float v3i = (yi[3] - (L30r * v0i + L30i * v0r) - (L31r * v1i + L31i * v1r)
                         - (L32r * v2i + L32i * v2r)) * i33;
      yr[0] = v0r; yi[0] = v0i; yr[1] = v1r; yi[1] = v1i;
      yr[2] = v2r; yi[2] = v2i; yr[3] = v3r; yi[3] = v3i;
    }

    // fp32 16-QAM table
    const float PRT[16] = { 0.31622776601683794f, 0.31622776601683794f, 0.9486832980505138f, 0.9486832980505138f,
                            0.31622776601683794f, 0.31622776601683794f, 0.9486832980505138f, 0.9486832980505138f,
                           -0.31622776601683794f,-0.31622776601683794f,-0.9486832980505138f,-0.9486832980505138f,
                           -0.31622776601683794f,-0.31622776601683794f,-0.9486832980505138f,-0.9486832980505138f };
    const float PIT[16] = { 0.31622776601683794f, 0.9486832980505138f, 0.31622776601683794f, 0.9486832980505138f,
                           -0.31622776601683794f,-0.9486832980505138f,-0.31622776601683794f,-0.9486832980505138f,
                            0.31622776601683794f, 0.9486832980505138f, 0.31622776601683794f, 0.9486832980505138f,
                           -0.31622776601683794f,-0.9486832980505138f,-0.31622776601683794f,-0.9486832980505138f };

    // only this plane's 2 UE columns (uniform branch per block)
    float lA[4], lB[4];
    if (plane == 0) {
      SOLVE_DEMAP(0, lA);
      SOLVE_DEMAP(1, lB);
    } else {
      SOLVE_DEMAP(2, lA);
      SOLVE_DEMAP(3, lB);
    }
    #pragma unroll
    for (int k = 0; k < 4; ++k) {
      sL[4 * s + k] = make_float2(lA[k], lB[k]);
    }
  }
  __syncthreads();

  // ================= phase 2: LDS-resident BP (2 codewords) ===============
  // own info-node state in registers
  float2 Ln[2], En[2];
  int pk0[2], pk1[2], pk2[2]; bool iok[2];
  #pragma unroll
  for (int i = 0; i < 2; ++i) {
    int n = tid + TB * i;
    iok[i] = n < KK;
    Ln[i] = make_float2(0.f, 0.f);
    En[i] = make_float2(1.f, 1.f);
    pk0[i] = pk1[i] = pk2[i] = 0;
    if (iok[i]) {
      float2 L = sL[n];
      Ln[i] = L;
      En[i] = make_float2(__expf(fminf(fmaxf(L.x, -55.f), 55.f)),
                          __expf(fminf(fmaxf(L.y, -55.f), 55.f)));
      int s0 = vlist[n * MAXVDEG], s1 = vlist[n * MAXVDEG + 1], s2 = vlist[n * MAXVDEG + 2];
      pk0[i] = (cinfo[s0] & 0xffff0000) | SWZ(s0);
      pk1[i] = (cinfo[s1] & 0xffff0000) | SWZ(s1);
      pk2[i] = (cinfo[s2] & 0xffff0000) | SWZ(s2);
    }
  }
  // per-check constant: tanh of the parity-node LLR.  Check tid (new id)
  // corresponds to ORIGINAL check cperm[tid]; its parity var is KK+orig.
  float2 qpar0, qpar1;
  {
    int oc0 = cperm[tid];
    float2 Lp0 = sL[KK + oc0];
    qpar0 = make_float2(tanh_half(Lp0.x), tanh_half(Lp0.y));
  }
  bool c1ok = (tid + TB) < MM;
  if (c1ok) {
    int oc1 = cperm[tid + TB];
    float2 Lp1 = sL[KK + oc1];
    qpar1 = make_float2(tanh_half(Lp1.x), tanh_half(Lp1.y));
  } else {
    qpar1 = make_float2(1.f, 1.f);
  }
  int beg0 = coff[tid],                  dnd0 = cdend[tid];
  int beg1 = c1ok ? coff[tid + TB]  : 0, dnd1 = c1ok ? cdend[tid + TB] : 0;
  __syncthreads();  // sL (= sT[0..1000)) reads done; sT writes may now begin

  for (int it = 0; it < NITERS; ++it) {
    // ---- pass 1: info-node var update ----
    if (it == 0) {
      #pragma unroll
      for (int i = 0; i < 2; ++i) {
        if (iok[i]) {
          float2 t = make_float2(tanh_half(Ln[i].x), tanh_half(Ln[i].y));
          sT[pk0[i] & 0xffff] = t;
          sT[pk1[i] & 0xffff] = t;
          sT[pk2[i] & 0xffff] = t;
        }
      }
    } else {
      #pragma unroll
      for (int i = 0; i < 2; ++i) {
        if (iok[i]) {
          int s0 = pk0[i] & 0xffff, c0 = ((unsigned)pk0[i]) >> 16;
          int s1 = pk1[i] & 0xffff, c1 = ((unsigned)pk1[i]) >> 16;
          int s2 = pk2[i] & 0xffff, c2 = ((unsigned)pk2[i]) >> 16;
          float2 P0 = sP[c0], P1 = sP[c1], P2 = sP[c2];
          float2 t0 = sT[s0], t1 = sT[s1], t2 = sT[s2];
          // lane x
          float p0 = pclip(P0.x, t0.x), p1 = pclip(P1.x, t1.x), p2 = pclip(P2.x, t2.x);
          float a0 = t0.x + p0, a1 = t1.x + p1, a2 = t2.x + p2;
          float b0 = t0.x - p0, b1 = t1.x - p1, b2 = t2.x - p2;
          float Ex = En[i].x;
          float A0 = Ex * (a1 * a2), A1 = Ex * (a0 * a2), A2 = Ex * (a0 * a1);
          float B0 = b1 * b2,        B1 = b0 * b2,        B2 = b0 * b1;
          float n0x = tfloor(__fdividef(A0 - B0, A0 + B0));
          float n1x = tfloor(__fdividef(A1 - B1, A1 + B1));
          float n2x = tfloor(__fdividef(A2 - B2, A2 + B2));
          // lane y
          float q0 = pclip(P0.y, t0.y), q1 = pclip(P1.y, t1.y), q2 = pclip(P2.y, t2.y);
          float c0a = t0.y + q0, c1a = t1.y + q1, c2a = t2.y + q2;
          float d0b = t0.y - q0, d1b = t1.y - q1, d2b = t2.y - q2;
          float Ey = En[i].y;
          float C0 = Ey * (c1a * c2a), C1 = Ey * (c0a * c2a), C2 = Ey * (c0a * c1a);
          float D0 = d1b * d2b,        D1 = d0b * d2b,        D2 = d0b * d1b;
          float n0y = tfloor(__fdividef(C0 - D0, C0 + D0));
          float n1y = tfloor(__fdividef(C1 - D1, C1 + D1));
          float n2y = tfloor(__fdividef(C2 - D2, C2 + D2));
          sT[s0] = make_float2(n0x, n0y);
          sT[s1] = make_float2(n1x, n1y);
          sT[s2] = make_float2(n2x, n2y);
        }
      }
    }
    __syncthreads();
    // ---- pass 2: per-check products (parity factor from register) ----
    // Sorted checks: uniform trip counts per wave; SWZ spreads the
    // power-of-2 slot strides across bank pairs.
    {
      float px = qpar0.x, py = qpar0.y;
      for (int e = beg0; e < dnd0; ++e) { float2 tt = sT[SWZ(e)]; px *= tt.x; py *= tt.y; }
      sP[tid] = make_float2(px, py);
      if (c1ok) {
        float qx = qpar1.x, qy = qpar1.y;
        for (int e = beg1; e < dnd1; ++e) { float2 tt = sT[SWZ(e)]; qx *= tt.x; qy *= tt.y; }
        sP[tid + TB] = make_float2(qx, qy);
      }
    }
    __syncthreads();
  }

  // ---- decide: additive log form (once) ----
  int cw0 = pairId * 2;
  float* o0 = out + (size_t)ncw * KK + (size_t)cw0 * KK;
  float* o1 = o0 + KK;
  #pragma unroll
  for (int i = 0; i < 2; ++i) {
    if (iok[i]) {
      int n = tid + TB * i;
      int s0 = pk0[i] & 0xffff, c0 = ((unsigned)pk0[i]) >> 16;
      int s1 = pk1[i] & 0xffff, c1 = ((unsigned)pk1[i]) >> 16;
      int s2 = pk2[i] & 0xffff, c2 = ((unsigned)pk2[i]) >> 16;
      float2 P0 = sP[c0], P1 = sP[c1], P2 = sP[c2];
      float2 t0 = sT[s0], t1 = sT[s1], t2 = sT[s2];
      float2 L = Ln[i];
      float ax = L.x + atanh2c(P0.x, t0.x) + atanh2c(P1.x, t1.x) + atanh2c(P2.x, t2.x);
      float ay = L.y + atanh2c(P0.y, t0.y) + atanh2c(P1.y, t1.y) + atanh2c(P2.y, t2.y);
      o0[n] = (ax < 0.0f) ? 1.0f : 0.0f;
      o1[n] = (ay < 0.0f) ? 1.0f : 0.0f;
    }
  }
}

// ---------------- launcher ----------------
extern "C" void kernel_launch(void* const* d_in, const int* in_sizes, int n_in,
                              void* d_out, int out_size, void* d_ws, size_t ws_size,
                              hipStream_t stream) {
  const float* ebno = (const float*)d_in[1];
  const int*   b    = (const int*)d_in[2];
  const int*   P    = (const int*)d_in[3];
  const int*   cn   = (const int*)d_in[4];
  const int*   vn   = (const int*)d_in[5];
  const float* h_re = (const float*)d_in[6];
  const float* h_im = (const float*)d_in[7];
  const float* nre  = (const float*)d_in[8];
  const float* nim  = (const float*)d_in[9];
  float* out = (float*)d_out;

  int E     = in_sizes[4];
  int batch = in_sizes[2] / (4 * KK);
  int ncw   = batch * 4;

  char* ws = (char*)d_ws;
  size_t off = 0;
  auto alloc = [&](size_t bytes) -> void* {
    void* p = ws + off;
    off += (bytes + 255) & ~(size_t)255;
    return p;
  };
  unsigned* Ppack  = (unsigned*)alloc((size_t)MM * 16 * 4);
  unsigned* bpack  = (unsigned*)alloc((size_t)ncw * 16 * 4);
  int*      coff   = (int*)alloc((size_t)(MM + 1) * 4);
  int*      cdend  = (int*)alloc((size_t)MM * 4);
  int*      cperm  = (int*)alloc((size_t)MM * 4);
  int*      cinfo  = (int*)alloc((size_t)EMAX * 4);
  int*      vlist  = (int*)alloc((size_t)NNODES * MAXVDEG * 4);
  double*   nobuf  = (double*)alloc(2 * 8);
  (void)ws_size; (void)n_in; (void)out_size;

  int packItems  = MM * 16 + ncw * 16;
  int packBlocks = (packItems + 511) / 512;
  int bfBlocks   = (ncw * KK + 511) / 512;
  int setupGrid  = 1 + packBlocks + bfBlocks;

  k_setup<<<dim3(setupGrid), dim3(512), 0, stream>>>(cn, vn, E, ebno, P, b, ncw,
                                                     cinfo, vlist, coff, cdend, cperm,
                                                     nobuf, Ppack, bpack, out, packBlocks);
  k_fused<<<dim3(ncw / 2), dim3(256), 0, stream>>>(h_re, h_im, nre, nim, nobuf,
                                                   bpack, Ppack, vlist, coff, cdend,
                                                   cperm, cinfo, out, ncw);
}

// Round 6
// 169.268 us; speedup vs baseline: 1.5737x; 1.0444x over previous
//
#include <hip/hip_runtime.h>
#include <math.h>

// Problem constants (from reference)
#define KK     500   // info bits
#define MM     500   // parity checks
#define NNODES 1000  // N = K + M variable nodes
#define NSYM   250   // N / BPS
#define NITERS 5
#define MAXVDEG 4    // info vars degree exactly 3 (row weight of P), parity vars 1
#define EMAX   2048  // E = 2000 slots (unpadded), round up
#define TB     256

// XOR bank swizzle on sT indices: involution, bijective on [0,2048).
#define SWZ(s) ((s) ^ (((s) >> 4) & 3))

// ---------------- setup: graph build + bit packing + bf output -------------
// Checks COUNTING-SORTED by total degree and relabeled (new id = rank):
// waves in BP pass-2 get uniform trip counts (no divergence).
__global__ void __launch_bounds__(512)
k_setup(const int* __restrict__ cn, const int* __restrict__ vn, int E,
        const float* __restrict__ ebno, const int* __restrict__ P,
        const int* __restrict__ b, int ncw,
        int* __restrict__ cinfo, int* __restrict__ vlist, int* __restrict__ coff,
        int* __restrict__ cdend, int* __restrict__ cperm,
        double* __restrict__ nobuf, unsigned* __restrict__ Ppack,
        unsigned* __restrict__ bpack, float* __restrict__ out, int packBlocks) {
  __shared__ int sdeg[512];   // orig check -> total degree
  __shared__ int scinv[512];  // orig check -> new id
  __shared__ int sdnew[512];  // new id -> degree
  __shared__ int sexcl[512];  // new id -> range begin
  __shared__ int ssc[512];
  __shared__ int scur[512];
  __shared__ int svc[NNODES];
  __shared__ int shist[64];
  __shared__ int shcur[64];
  int tid = threadIdx.x;
  int bx = blockIdx.x;

  if (bx == 0) {
    sdeg[tid] = 0;
    for (int n = tid; n < NNODES; n += 512) svc[n] = 0;
    if (tid < 64) { shist[tid] = 0; shcur[tid] = 0; }
    __syncthreads();
    for (int e = tid; e < E; e += 512) atomicAdd(&sdeg[cn[e]], 1);
    __syncthreads();
    int d = (tid < MM) ? sdeg[tid] : 0;
    if (tid < MM) atomicAdd(&shist[d], 1);
    __syncthreads();
    if (tid == 0) {
      int acc = 0;
      for (int i = 0; i < 64; ++i) { int h = shist[i]; shist[i] = acc; shcur[i] = acc; acc += h; }
    }
    __syncthreads();
    if (tid < MM) {
      int nid = atomicAdd(&shcur[d], 1);
      scinv[tid] = nid;
      cperm[nid] = tid;          // new -> orig (for parity-LLR lookup)
      sdnew[nid] = d;
    }
    __syncthreads();
    // scan (unpadded) lengths over NEW order
    int v = (tid < MM) ? sdnew[tid] : 0;
    ssc[tid] = v;
    __syncthreads();
    for (int o = 1; o < 512; o <<= 1) {
      int x = (tid >= o) ? ssc[tid - o] : 0;
      __syncthreads();
      ssc[tid] += x;
      __syncthreads();
    }
    int excl = ssc[tid] - v;
    sexcl[tid] = excl;
    scur[tid] = excl;
    if (tid < MM) {
      coff[tid]  = excl;
      cdend[tid] = excl + sdnew[tid] - 1;  // product loop: [beg, dend) = info edges
      if (tid == MM - 1) coff[MM] = ssc[tid];
    }
    __syncthreads();
    for (int e = tid; e < E; e += 512) {
      int c = cn[e], n = vn[e];
      int nc = scinv[c];
      int slot;
      if (n >= KK) {
        slot = sexcl[nc] + sdeg[c] - 1;    // parity edge -> last slot
      } else {
        slot = atomicAdd(&scur[nc], 1);    // info edges fill [beg, beg+d-1)
      }
      cinfo[slot] = (nc << 16) | n;
      if (n < KK) {
        int t = atomicAdd(&svc[n], 1);
        if (t < MAXVDEG) vlist[n * MAXVDEG + t] = slot;
      }
    }
    if (tid == 0) {
      double no = 1.0 / (pow(10.0, (double)ebno[0] * 0.1) * 2.0);  // BPS*RATE = 2
      nobuf[0] = no;
      nobuf[1] = sqrt(no * 0.5);
    }
    return;
  }

  if (bx <= packBlocks) {
    int id = (bx - 1) * 512 + tid;
    if (id < MM * 16) {
      int j = id >> 4, w = id & 15;
      unsigned word = 0u;
      int base = w * 32;
      for (int bit = 0; bit < 32; ++bit) {
        int i = base + bit;
        if (i < KK && P[i * MM + j] != 0) word |= (1u << bit);
      }
      Ppack[j * 16 + w] = word;
    } else {
      int id2 = id - MM * 16;
      if (id2 < ncw * 16) {
        int cw = id2 >> 4, w = id2 & 15;
        unsigned word = 0u;
        int base = w * 32;
        for (int bit = 0; bit < 32; ++bit) {
          int i = base + bit;
          if (i < KK && b[cw * KK + i] != 0) word |= (1u << bit);
        }
        bpack[cw * 16 + w] = word;
      }
    }
    return;
  }

  int id = (bx - 1 - packBlocks) * 512 + tid;
  if (id < ncw * KK) out[id] = (float)b[id];
}

// ---------------- 16-QAM constellation (fp32 TX symbol) --------------------
__device__ __forceinline__ void qam_pointf(int p, float& re, float& im) {
  const float s = 0.31622776601683794f;  // 1/sqrt(10)
  int b0 = (p >> 3) & 1, b1 = (p >> 2) & 1, b2 = (p >> 1) & 1, b3 = p & 1;
  re = (float)((1 - 2 * b0) * (2 - (1 - 2 * b2))) * s;
  im = (float)((1 - 2 * b1) * (2 - (1 - 2 * b3))) * s;
}

// ---------------- BP helpers ----------------
__device__ __forceinline__ float tanh_half(float m) {
  float mc = fminf(fmaxf(m, -19.8f), 19.8f);
  float e = __expf(mc);
  float t = 1.0f - __fdividef(2.0f, e + 1.0f);
  return (t >= 0.0f) ? fmaxf(t, 1e-7f) : fminf(t, -1e-7f);
}
__device__ __forceinline__ float4 tanh_half4(float4 m) {
  return make_float4(tanh_half(m.x), tanh_half(m.y), tanh_half(m.z), tanh_half(m.w));
}
__device__ __forceinline__ float pclip(float P, float t) {
  return copysignf(fminf(fabsf(P), 0.999999f * fabsf(t)), P);
}
__device__ __forceinline__ float tfloor(float t) {
  return (t >= 0.0f) ? fmaxf(t, 1e-7f) : fminf(t, -1e-7f);
}
__device__ __forceinline__ float atanh2c(float P, float t) {
  float r = __fdividef(P, t);
  r = fminf(fmaxf(r, -0.999999f), 0.999999f);
  return __logf(__fdividef(1.0f + r, 1.0f - r));
}

// per-column forward solve + max-log demap, column index J compile-time.
#define SOLVE_DEMAP(J, Lout) {                                                          \
  float u0r = Hr[0][J] * i00,               u0i = Hi[0][J] * i00;                       \
  float u1r = (Hr[1][J] - (L10r * u0r - L10i * u0i)) * i11;                             \
  float u1i = (Hi[1][J] - (L10r * u0i + L10i * u0r)) * i11;                             \
  float u2r = (Hr[2][J] - (L20r * u0r - L20i * u0i) - (L21r * u1r - L21i * u1i)) * i22; \
  float u2i = (Hi[2][J] - (L20r * u0i + L20i * u0r) - (L21r * u1i + L21i * u1r)) * i22; \
  float u3r = (Hr[3][J] - (L30r * u0r - L30i * u0i) - (L31r * u1r - L31i * u1i)         \
                        - (L32r * u2r - L32i * u2i)) * i33;                             \
  float u3i = (Hi[3][J] - (L30r * u0i + L30i * u0r) - (L31r * u1i + L31i * u1r)         \
                        - (L32r * u2i + L32i * u2r)) * i33;                             \
  float dj = (u0r * u0r + u0i * u0i) + (u1r * u1r + u1i * u1i)                          \
           + (u2r * u2r + u2i * u2i) + (u3r * u3r + u3i * u3i);                         \
  float rr = (u0r * yr[0] + u0i * yi[0]) + (u1r * yr[1] + u1i * yi[1])                  \
           + (u2r * yr[2] + u2i * yi[2]) + (u3r * yr[3] + u3i * yi[3]);                 \
  float ri = (u0r * yi[0] - u0i * yr[0]) + (u1r * yi[1] - u1i * yr[1])                  \
           + (u2r * yi[2] - u2i * yr[2]) + (u3r * yi[3] - u3i * yr[3]);                 \
  float rdj = __fdividef(1.0f, dj);                                                    \
  float xhr = rr * rdj, xhi = ri * rdj;                                                \
  float gap = 1.0f - dj;                                                               \
  float inoe = __fdividef(dj, fmaxf(gap, dj * 1e-12f));                                \
  float m0[4] = {-1e30f, -1e30f, -1e30f, -1e30f};                                      \
  float m1[4] = {-1e30f, -1e30f, -1e30f, -1e30f};                                      \
  _Pragma("unroll")                                                                    \
  for (int p = 0; p < 16; ++p) {                                                       \
    float dr = xhr - PRT[p], di = xhi - PIT[p];                                        \
    float met = -(dr * dr + di * di) * inoe;                                           \
    _Pragma("unroll")                                                                  \
    for (int k = 0; k < 4; ++k) {                                                      \
      if ((p >> (3 - k)) & 1) m1[k] = fmaxf(m1[k], met);                               \
      else                    m0[k] = fmaxf(m0[k], met);                               \
    }                                                                                  \
  }                                                                                    \
  _Pragma("unroll")                                                                    \
  for (int k = 0; k < 4; ++k) Lout[k] = m0[k] - m1[k];                                 \
}

// variable-node update for one float4 component C (codeword C of 4)
#define VUPD(C) {                                                                      \
  float p0 = pclip(P0.C, t0.C), p1 = pclip(P1.C, t1.C), p2 = pclip(P2.C, t2.C);        \
  float a0 = t0.C + p0, a1 = t1.C + p1, a2 = t2.C + p2;                                \
  float b0 = t0.C - p0, b1 = t1.C - p1, b2 = t2.C - p2;                                \
  float Ec = En[i].C;                                                                  \
  float A0 = Ec * (a1 * a2), A1 = Ec * (a0 * a2), A2 = Ec * (a0 * a1);                 \
  float B0 = b1 * b2,        B1 = b0 * b2,        B2 = b0 * b1;                        \
  n0.C = tfloor(__fdividef(A0 - B0, A0 + B0));                                         \
  n1.C = tfloor(__fdividef(A1 - B1, A1 + B1));                                         \
  n2.C = tfloor(__fdividef(A2 - B2, A2 + B2));                                         \
}

// ---------------- fused LMMSE + BP, ONE block per bt (4 codewords) ---------
// Round-17: kills the phase-1 duplication.  Previously each bt had 2 plane
// blocks BOTH running the shared chain (H load, encode of all 4 UEs, y,
// Gram, Cholesky, y-solve) -- ~70% of phase-1 executed twice.  Now one
// block runs the chain once, demaps all 4 columns (every result used), and
// phase-2 is float4-lane BP over the bt's 4 codewords.  Total BP work
// unchanged; phase-1 VALU total -35%; H/noise fetch halves.
// LDS = 32 KB sT4 + 8 KB sP4 = 40 KB -> 4 blocks/CU = 16 waves/CU, at or
// above the measured ~14 waves/CU of the pair version.
// __launch_bounds__(256,4): allocator cap 128 VGPR (R4 lesson: floor 8
// forced 32 VGPR and spilled everything -> 205 MB scratch writes).
__global__ void __launch_bounds__(256, 4)
k_fused(const float* __restrict__ h_re, const float* __restrict__ h_im,
        const float* __restrict__ n_re, const float* __restrict__ n_im,
        const double* __restrict__ nobuf,
        const unsigned* __restrict__ bpack, const unsigned* __restrict__ Ppack,
        const int* __restrict__ vlist, const int* __restrict__ coff,
        const int* __restrict__ cdend, const int* __restrict__ cperm,
        const int* __restrict__ cinfo, float* __restrict__ out, int ncw) {
  __shared__ float4 sT[EMAX];    // tanh(v2c/2) per edge slot x 4 cw (32 KB)
  __shared__ float4 sP[512];     // per-check product of tanh x 4 cw (8 KB)
  float4* sL = sT;               // staged LLRs alias (first NNODES entries)

  int tid = threadIdx.x;
  int bt = blockIdx.x;

  // ================= phase 1: LMMSE for this bt's 250 symbols ==============
  if (tid < NSYM) {
    int t = bt * NSYM + tid;
    int s = tid;

    float no = (float)nobuf[0];
    float sq = (float)nobuf[1];
    const float is2 = 0.70710678118654752f;  // 1/sqrt(2)

    float Hr[4][4], Hi[4][4];
    {
      const float4* hr4 = (const float4*)h_re;
      const float4* hi4 = (const float4*)h_im;
      #pragma unroll
      for (int i = 0; i < 4; ++i) {
        float4 a = hr4[t * 4 + i], c = hi4[t * 4 + i];
        Hr[i][0] = a.x * is2; Hr[i][1] = a.y * is2;
        Hr[i][2] = a.z * is2; Hr[i][3] = a.w * is2;
        Hi[i][0] = c.x * is2; Hi[i][1] = c.y * is2;
        Hi[i][2] = c.z * is2; Hi[i][3] = c.w * is2;
      }
    }

    // transmitted symbols: encode+map inline
    float xr[4], xi[4];
    #pragma unroll
    for (int ue = 0; ue < 4; ++ue) {
      const unsigned* bp = bpack + (bt * 4 + ue) * 16;
      int v = 0;
      #pragma unroll
      for (int k = 0; k < 4; ++k) {
        int n = 4 * s + k;
        int bit;
        if (n < KK) {
          bit = (bp[n >> 5] >> (n & 31)) & 1;
        } else {
          const unsigned* pp = Ppack + (n - KK) * 16;
          int cnt = 0;
          #pragma unroll
          for (int w = 0; w < 16; ++w) cnt += __popc(bp[w] & pp[w]);
          bit = cnt & 1;
        }
        v = (v << 1) | bit;  // MSB-first: weights 8,4,2,1
      }
      qam_pointf(v, xr[ue], xi[ue]);
    }

    // y = H x + w
    float yr[4], yi[4];
    {
      float4 wr = ((const float4*)n_re)[t];
      float4 wi = ((const float4*)n_im)[t];
      float wrv[4] = {wr.x, wr.y, wr.z, wr.w};
      float wiv[4] = {wi.x, wi.y, wi.z, wi.w};
      #pragma unroll
      for (int i = 0; i < 4; ++i) {
        float ar = wrv[i] * sq;
        float ai = wiv[i] * sq;
        #pragma unroll
        for (int j = 0; j < 4; ++j) {
          ar += Hr[i][j] * xr[j] - Hi[i][j] * xi[j];
          ai += Hr[i][j] * xi[j] + Hi[i][j] * xr[j];
        }
        yr[i] = ar; yi[i] = ai;
      }
    }

    // A = H H^H + no I, lower triangle, into scalars
    auto dotc = [&](int i, int j, float& ar, float& ai) {
      float r = 0.0f, m = 0.0f;
      #pragma unroll
      for (int k = 0; k < 4; ++k) {
        r += Hr[i][k] * Hr[j][k] + Hi[i][k] * Hi[j][k];
        m += Hi[i][k] * Hr[j][k] - Hr[i][k] * Hi[j][k];
      }
      ar = r; ai = m;
    };
    float a00, a11, a22, a33, dum;
    float a10r, a10i, a20r, a20i, a21r, a21i, a30r, a30i, a31r, a31i, a32r, a32i;
    dotc(0, 0, a00, dum);  a00 += no;
    dotc(1, 0, a10r, a10i);
    dotc(1, 1, a11, dum);  a11 += no;
    dotc(2, 0, a20r, a20i);
    dotc(2, 1, a21r, a21i);
    dotc(2, 2, a22, dum);  a22 += no;
    dotc(3, 0, a30r, a30i);
    dotc(3, 1, a31r, a31i);
    dotc(3, 2, a32r, a32i);
    dotc(3, 3, a33, dum);  a33 += no;

    // Cholesky in inverse-diagonal form
    float i00 = rsqrtf(a00);
    float L10r = a10r * i00, L10i = a10i * i00;
    float L20r = a20r * i00, L20i = a20i * i00;
    float L30r = a30r * i00, L30i = a30i * i00;
    float d11 = a11 - (L10r * L10r + L10i * L10i);
    float i11 = rsqrtf(d11);
    float L21r = (a21r - (L20r * L10r + L20i * L10i)) * i11;
    float L21i = (a21i - (L20i * L10r - L20r * L10i)) * i11;
    float L31r = (a31r - (L30r * L10r + L30i * L10i)) * i11;
    float L31i = (a31i - (L30i * L10r - L30r * L10i)) * i11;
    float d22 = a22 - (L20r * L20r + L20i * L20i) - (L21r * L21r + L21i * L21i);
    float i22 = rsqrtf(d22);
    float L32r = (a32r - (L30r * L20r + L30i * L20i) - (L31r * L21r + L31i * L21i)) * i22;
    float L32i = (a32i - (L30i * L20r - L30r * L20i) - (L31i * L21r - L31r * L21i)) * i22;
    float d33 = a33 - (L30r * L30r + L30i * L30i) - (L31r * L31r + L31i * L31i)
                    - (L32r * L32r + L32i * L32i);
    float i33 = rsqrtf(d33);

    // forward solve on y only: v = L^{-1} y (in place)
    {
      float v0r = yr[0] * i00,               v0i = yi[0] * i00;
      float v1r = (yr[1] - (L10r * v0r - L10i * v0i)) * i11;
      float v1i = (yi[1] - (L10r * v0i + L10i * v0r)) * i11;
      float v2r = (yr[2] - (L20r * v0r - L20i * v0i) - (L21r * v1r - L21i * v1i)) * i22;
      float v2i = (yi[2] - (L20r * v0i + L20i * v0r) - (L21r * v1i + L21i * v1r)) * i22;
      float v3r = (yr[3] - (L30r * v0r - L30i * v0i) - (L31r * v1r - L31i * v1i)
                         - (L32r * v2r - L32i * v2i)) * i33;
      float v3i = (yi[3] - (L30r * v0i + L30i * v0r) - (L31r * v1i + L31i * v1r)
                         - (L32r * v2i + L32i * v2r)) * i33;
      yr[0] = v0r; yi[0] = v0i; yr[1] = v1r; yi[1] = v1i;
      yr[2] = v2r; yi[2] = v2i; yr[3] = v3r; yi[3] = v3i;
    }

    // fp32 16-QAM table
    const float PRT[16] = { 0.31622776601683794f, 0.31622776601683794f, 0.9486832980505138f, 0.9486832980505138f,
                            0.31622776601683794f, 0.31622776601683794f, 0.9486832980505138f, 0.9486832980505138f,
                           -0.31622776601683794f,-0.31622776601683794f,-0.9486832980505138f,-0.9486832980505138f,
                           -0.31622776601683794f,-0.31622776601683794f,-0.9486832980505138f,-0.9486832980505138f };
    const float PIT[16] = { 0.31622776601683794f, 0.9486832980505138f, 0.31622776601683794f, 0.9486832980505138f,
                           -0.31622776601683794f,-0.9486832980505138f,-0.31622776601683794f,-0.9486832980505138f,
                            0.31622776601683794f, 0.9486832980505138f, 0.31622776601683794f, 0.9486832980505138f,
                           -0.31622776601683794f,-0.9486832980505138f,-0.31622776601683794f,-0.9486832980505138f };

    // all 4 UE columns (each feeds one codeword lane)
    float l0[4], l1[4], l2[4], l3[4];
    SOLVE_DEMAP(0, l0);
    SOLVE_DEMAP(1, l1);
    SOLVE_DEMAP(2, l2);
    SOLVE_DEMAP(3, l3);
    #pragma unroll
    for (int k = 0; k < 4; ++k) {
      sL[4 * s + k] = make_float4(l0[k], l1[k], l2[k], l3[k]);
    }
  }
  __syncthreads();

  // ================= phase 2: LDS-resident BP (4 codewords) ===============
  // own info-node state in registers
  float4 Ln[2], En[2];
  int pk0[2], pk1[2], pk2[2]; bool iok[2];
  #pragma unroll
  for (int i = 0; i < 2; ++i) {
    int n = tid + TB * i;
    iok[i] = n < KK;
    Ln[i] = make_float4(0.f, 0.f, 0.f, 0.f);
    En[i] = make_float4(1.f, 1.f, 1.f, 1.f);
    pk0[i] = pk1[i] = pk2[i] = 0;
    if (iok[i]) {
      float4 L = sL[n];
      Ln[i] = L;
      En[i] = make_float4(__expf(fminf(fmaxf(L.x, -55.f), 55.f)),
                          __expf(fminf(fmaxf(L.y, -55.f), 55.f)),
                          __expf(fminf(fmaxf(L.z, -55.f), 55.f)),
                          __expf(fminf(fmaxf(L.w, -55.f), 55.f)));
      int s0 = vlist[n * MAXVDEG], s1 = vlist[n * MAXVDEG + 1], s2 = vlist[n * MAXVDEG + 2];
      pk0[i] = (cinfo[s0] & 0xffff0000) | SWZ(s0);
      pk1[i] = (cinfo[s1] & 0xffff0000) | SWZ(s1);
      pk2[i] = (cinfo[s2] & 0xffff0000) | SWZ(s2);
    }
  }
  // per-check constant: tanh of the parity-node LLR.  Check tid (new id)
  // corresponds to ORIGINAL check cperm[tid]; its parity var is KK+orig.
  float4 qpar0, qpar1;
  {
    int oc0 = cperm[tid];
    qpar0 = tanh_half4(sL[KK + oc0]);
  }
  bool c1ok = (tid + TB) < MM;
  if (c1ok) {
    int oc1 = cperm[tid + TB];
    qpar1 = tanh_half4(sL[KK + oc1]);
  } else {
    qpar1 = make_float4(1.f, 1.f, 1.f, 1.f);
  }
  int beg0 = coff[tid],                  dnd0 = cdend[tid];
  int beg1 = c1ok ? coff[tid + TB]  : 0, dnd1 = c1ok ? cdend[tid + TB] : 0;
  __syncthreads();  // sL (= sT[0..1000)) reads done; sT writes may now begin

  for (int it = 0; it < NITERS; ++it) {
    // ---- pass 1: info-node var update ----
    if (it == 0) {
      #pragma unroll
      for (int i = 0; i < 2; ++i) {
        if (iok[i]) {
          float4 t = tanh_half4(Ln[i]);
          sT[pk0[i] & 0xffff] = t;
          sT[pk1[i] & 0xffff] = t;
          sT[pk2[i] & 0xffff] = t;
        }
      }
    } else {
      #pragma unroll
      for (int i = 0; i < 2; ++i) {
        if (iok[i]) {
          int s0 = pk0[i] & 0xffff, c0 = ((unsigned)pk0[i]) >> 16;
          int s1 = pk1[i] & 0xffff, c1 = ((unsigned)pk1[i]) >> 16;
          int s2 = pk2[i] & 0xffff, c2 = ((unsigned)pk2[i]) >> 16;
          float4 P0 = sP[c0], P1 = sP[c1], P2 = sP[c2];
          float4 t0 = sT[s0], t1 = sT[s1], t2 = sT[s2];
          float4 n0, n1, n2;
          VUPD(x); VUPD(y); VUPD(z); VUPD(w);
          sT[s0] = n0;
          sT[s1] = n1;
          sT[s2] = n2;
        }
      }
    }
    __syncthreads();
    // ---- pass 2: per-check products (parity factor from register) ----
    // Sorted checks: uniform trip counts per wave.
    {
      float4 p = qpar0;
      for (int e = beg0; e < dnd0; ++e) {
        float4 tt = sT[SWZ(e)];
        p.x *= tt.x; p.y *= tt.y; p.z *= tt.z; p.w *= tt.w;
      }
      sP[tid] = p;
      if (c1ok) {
        float4 q = qpar1;
        for (int e = beg1; e < dnd1; ++e) {
          float4 tt = sT[SWZ(e)];
          q.x *= tt.x; q.y *= tt.y; q.z *= tt.z; q.w *= tt.w;
        }
        sP[tid + TB] = q;
      }
    }
    __syncthreads();
  }

  // ---- decide: additive log form (once) ----
  int cw0 = bt * 4;
  float* o0 = out + (size_t)ncw * KK + (size_t)cw0 * KK;
  float* o1 = o0 + KK;
  float* o2 = o1 + KK;
  float* o3 = o2 + KK;
  #pragma unroll
  for (int i = 0; i < 2; ++i) {
    if (iok[i]) {
      int n = tid + TB * i;
      int s0 = pk0[i] & 0xffff, c0 = ((unsigned)pk0[i]) >> 16;
      int s1 = pk1[i] & 0xffff, c1 = ((unsigned)pk1[i]) >> 16;
      int s2 = pk2[i] & 0xffff, c2 = ((unsigned)pk2[i]) >> 16;
      float4 P0 = sP[c0], P1 = sP[c1], P2 = sP[c2];
      float4 t0 = sT[s0], t1 = sT[s1], t2 = sT[s2];
      float4 L = Ln[i];
      float ax = L.x + atanh2c(P0.x, t0.x) + atanh2c(P1.x, t1.x) + atanh2c(P2.x, t2.x);
      float ay = L.y + atanh2c(P0.y, t0.y) + atanh2c(P1.y, t1.y) + atanh2c(P2.y, t2.y);
      float az = L.z + atanh2c(P0.z, t0.z) + atanh2c(P1.z, t1.z) + atanh2c(P2.z, t2.z);
      float aw = L.w + atanh2c(P0.w, t0.w) + atanh2c(P1.w, t1.w) + atanh2c(P2.w, t2.w);
      o0[n] = (ax < 0.0f) ? 1.0f : 0.0f;
      o1[n] = (ay < 0.0f) ? 1.0f : 0.0f;
      o2[n] = (az < 0.0f) ? 1.0f : 0.0f;
      o3[n] = (aw < 0.0f) ? 1.0f : 0.0f;
    }
  }
}

// ---------------- launcher ----------------
extern "C" void kernel_launch(void* const* d_in, const int* in_sizes, int n_in,
                              void* d_out, int out_size, void* d_ws, size_t ws_size,
                              hipStream_t stream) {
  const float* ebno = (const float*)d_in[1];
  const int*   b    = (const int*)d_in[2];
  const int*   P    = (const int*)d_in[3];
  const int*   cn   = (const int*)d_in[4];
  const int*   vn   = (const int*)d_in[5];
  const float* h_re = (const float*)d_in[6];
  const float* h_im = (const float*)d_in[7];
  const float* nre  = (const float*)d_in[8];
  const float* nim  = (const float*)d_in[9];
  float* out = (float*)d_out;

  int E     = in_sizes[4];
  int batch = in_sizes[2] / (4 * KK);
  int ncw   = batch * 4;

  char* ws = (char*)d_ws;
  size_t off = 0;
  auto alloc = [&](size_t bytes) -> void* {
    void* p = ws + off;
    off += (bytes + 255) & ~(size_t)255;
    return p;
  };
  unsigned* Ppack  = (unsigned*)alloc((size_t)MM * 16 * 4);
  unsigned* bpack  = (unsigned*)alloc((size_t)ncw * 16 * 4);
  int*      coff   = (int*)alloc((size_t)(MM + 1) * 4);
  int*      cdend  = (int*)alloc((size_t)MM * 4);
  int*      cperm  = (int*)alloc((size_t)MM * 4);
  int*      cinfo  = (int*)alloc((size_t)EMAX * 4);
  int*      vlist  = (int*)alloc((size_t)NNODES * MAXVDEG * 4);
  double*   nobuf  = (double*)alloc(2 * 8);
  (void)ws_size; (void)n_in; (void)out_size;

  int packItems  = MM * 16 + ncw * 16;
  int packBlocks = (packItems + 511) / 512;
  int bfBlocks   = (ncw * KK + 511) / 512;
  int setupGrid  = 1 + packBlocks + bfBlocks;

  k_setup<<<dim3(setupGrid), dim3(512), 0, stream>>>(cn, vn, E, ebno, P, b, ncw,
                                                     cinfo, vlist, coff, cdend, cperm,
                                                     nobuf, Ppack, bpack, out, packBlocks);
  k_fused<<<dim3(batch), dim3(256), 0, stream>>>(h_re, h_im, nre, nim, nobuf,
                                                 bpack, Ppack, vlist, coff, cdend,
                                                 cperm, cinfo, out, ncw);
}

// Round 7
// 168.328 us; speedup vs baseline: 1.5825x; 1.0056x over previous
//
#include <hip/hip_runtime.h>
#include <math.h>

// Problem constants (from reference)
#define KK     500   // info bits
#define MM     500   // parity checks
#define NNODES 1000  // N = K + M variable nodes
#define NSYM   250   // N / BPS
#define NITERS 5
#define MAXVDEG 4    // info vars degree exactly 3 (row weight of P), parity vars 1
#define EMAX   2048  // E = 2000 slots (unpadded), round up
#define TB     512   // one node + one check per thread

// XOR bank swizzle on sT indices: involution, bijective on [0,2048).
#define SWZ(s) ((s) ^ (((s) >> 4) & 3))

// ---------------- setup: graph build + bit packing + bf output -------------
// Checks COUNTING-SORTED by total degree and relabeled (new id = rank):
// waves in BP pass-2 get uniform trip counts (no divergence).
__global__ void __launch_bounds__(512)
k_setup(const int* __restrict__ cn, const int* __restrict__ vn, int E,
        const float* __restrict__ ebno, const int* __restrict__ P,
        const int* __restrict__ b, int ncw,
        int* __restrict__ cinfo, int* __restrict__ vlist, int* __restrict__ coff,
        int* __restrict__ cdend, int* __restrict__ cperm,
        double* __restrict__ nobuf, unsigned* __restrict__ Ppack,
        unsigned* __restrict__ bpack, float* __restrict__ out, int packBlocks) {
  __shared__ int sdeg[512];   // orig check -> total degree
  __shared__ int scinv[512];  // orig check -> new id
  __shared__ int sdnew[512];  // new id -> degree
  __shared__ int sexcl[512];  // new id -> range begin
  __shared__ int ssc[512];
  __shared__ int scur[512];
  __shared__ int svc[NNODES];
  __shared__ int shist[64];
  __shared__ int shcur[64];
  int tid = threadIdx.x;
  int bx = blockIdx.x;

  if (bx == 0) {
    sdeg[tid] = 0;
    for (int n = tid; n < NNODES; n += 512) svc[n] = 0;
    if (tid < 64) { shist[tid] = 0; shcur[tid] = 0; }
    __syncthreads();
    for (int e = tid; e < E; e += 512) atomicAdd(&sdeg[cn[e]], 1);
    __syncthreads();
    int d = (tid < MM) ? sdeg[tid] : 0;
    if (tid < MM) atomicAdd(&shist[d], 1);
    __syncthreads();
    if (tid == 0) {
      int acc = 0;
      for (int i = 0; i < 64; ++i) { int h = shist[i]; shist[i] = acc; shcur[i] = acc; acc += h; }
    }
    __syncthreads();
    if (tid < MM) {
      int nid = atomicAdd(&shcur[d], 1);
      scinv[tid] = nid;
      cperm[nid] = tid;          // new -> orig (for parity-LLR lookup)
      sdnew[nid] = d;
    }
    __syncthreads();
    // scan (unpadded) lengths over NEW order
    int v = (tid < MM) ? sdnew[tid] : 0;
    ssc[tid] = v;
    __syncthreads();
    for (int o = 1; o < 512; o <<= 1) {
      int x = (tid >= o) ? ssc[tid - o] : 0;
      __syncthreads();
      ssc[tid] += x;
      __syncthreads();
    }
    int excl = ssc[tid] - v;
    sexcl[tid] = excl;
    scur[tid] = excl;
    if (tid < MM) {
      coff[tid]  = excl;
      cdend[tid] = excl + sdnew[tid] - 1;  // product loop: [beg, dend) = info edges
      if (tid == MM - 1) coff[MM] = ssc[tid];
    }
    __syncthreads();
    for (int e = tid; e < E; e += 512) {
      int c = cn[e], n = vn[e];
      int nc = scinv[c];
      int slot;
      if (n >= KK) {
        slot = sexcl[nc] + sdeg[c] - 1;    // parity edge -> last slot
      } else {
        slot = atomicAdd(&scur[nc], 1);    // info edges fill [beg, beg+d-1)
      }
      cinfo[slot] = (nc << 16) | n;
      if (n < KK) {
        int t = atomicAdd(&svc[n], 1);
        if (t < MAXVDEG) vlist[n * MAXVDEG + t] = slot;
      }
    }
    if (tid == 0) {
      double no = 1.0 / (pow(10.0, (double)ebno[0] * 0.1) * 2.0);  // BPS*RATE = 2
      nobuf[0] = no;
      nobuf[1] = sqrt(no * 0.5);
    }
    return;
  }

  if (bx <= packBlocks) {
    int id = (bx - 1) * 512 + tid;
    if (id < MM * 16) {
      int j = id >> 4, w = id & 15;
      unsigned word = 0u;
      int base = w * 32;
      for (int bit = 0; bit < 32; ++bit) {
        int i = base + bit;
        if (i < KK && P[i * MM + j] != 0) word |= (1u << bit);
      }
      Ppack[j * 16 + w] = word;
    } else {
      int id2 = id - MM * 16;
      if (id2 < ncw * 16) {
        int cw = id2 >> 4, w = id2 & 15;
        unsigned word = 0u;
        int base = w * 32;
        for (int bit = 0; bit < 32; ++bit) {
          int i = base + bit;
          if (i < KK && b[cw * KK + i] != 0) word |= (1u << bit);
        }
        bpack[cw * 16 + w] = word;
      }
    }
    return;
  }

  int id = (bx - 1 - packBlocks) * 512 + tid;
  if (id < ncw * KK) out[id] = (float)b[id];
}

// ---------------- 16-QAM constellation (fp32 TX symbol) --------------------
__device__ __forceinline__ void qam_pointf(int p, float& re, float& im) {
  const float s = 0.31622776601683794f;  // 1/sqrt(10)
  int b0 = (p >> 3) & 1, b1 = (p >> 2) & 1, b2 = (p >> 1) & 1, b3 = p & 1;
  re = (float)((1 - 2 * b0) * (2 - (1 - 2 * b2))) * s;
  im = (float)((1 - 2 * b1) * (2 - (1 - 2 * b3))) * s;
}

// ---------------- BP helpers ----------------
__device__ __forceinline__ float tanh_half(float m) {
  float mc = fminf(fmaxf(m, -19.8f), 19.8f);
  float e = __expf(mc);
  float t = 1.0f - __fdividef(2.0f, e + 1.0f);
  return (t >= 0.0f) ? fmaxf(t, 1e-7f) : fminf(t, -1e-7f);
}
__device__ __forceinline__ float4 tanh_half4(float4 m) {
  return make_float4(tanh_half(m.x), tanh_half(m.y), tanh_half(m.z), tanh_half(m.w));
}
__device__ __forceinline__ float pclip(float P, float t) {
  return copysignf(fminf(fabsf(P), 0.999999f * fabsf(t)), P);
}
__device__ __forceinline__ float tfloor(float t) {
  return (t >= 0.0f) ? fmaxf(t, 1e-7f) : fminf(t, -1e-7f);
}
__device__ __forceinline__ float atanh2c(float P, float t) {
  float r = __fdividef(P, t);
  r = fminf(fmaxf(r, -0.999999f), 0.999999f);
  return __logf(__fdividef(1.0f + r, 1.0f - r));
}

// per-column forward solve + max-log demap, column index J compile-time.
#define SOLVE_DEMAP(J, Lout) {                                                          \
  float u0r = Hr[0][J] * i00,               u0i = Hi[0][J] * i00;                       \
  float u1r = (Hr[1][J] - (L10r * u0r - L10i * u0i)) * i11;                             \
  float u1i = (Hi[1][J] - (L10r * u0i + L10i * u0r)) * i11;                             \
  float u2r = (Hr[2][J] - (L20r * u0r - L20i * u0i) - (L21r * u1r - L21i * u1i)) * i22; \
  float u2i = (Hi[2][J] - (L20r * u0i + L20i * u0r) - (L21r * u1i + L21i * u1r)) * i22; \
  float u3r = (Hr[3][J] - (L30r * u0r - L30i * u0i) - (L31r * u1r - L31i * u1i)         \
                        - (L32r * u2r - L32i * u2i)) * i33;                             \
  float u3i = (Hi[3][J] - (L30r * u0i + L30i * u0r) - (L31r * u1i + L31i * u1r)         \
                        - (L32r * u2i + L32i * u2r)) * i33;                             \
  float dj = (u0r * u0r + u0i * u0i) + (u1r * u1r + u1i * u1i)                          \
           + (u2r * u2r + u2i * u2i) + (u3r * u3r + u3i * u3i);                         \
  float rr = (u0r * yr[0] + u0i * yi[0]) + (u1r * yr[1] + u1i * yi[1])                  \
           + (u2r * yr[2] + u2i * yi[2]) + (u3r * yr[3] + u3i * yi[3]);                 \
  float ri = (u0r * yi[0] - u0i * yr[0]) + (u1r * yi[1] - u1i * yr[1])                  \
           + (u2r * yi[2] - u2i * yr[2]) + (u3r * yi[3] - u3i * yr[3]);                 \
  float rdj = __fdividef(1.0f, dj);                                                    \
  float xhr = rr * rdj, xhi = ri * rdj;                                                \
  float gap = 1.0f - dj;                                                               \
  float inoe = __fdividef(dj, fmaxf(gap, dj * 1e-12f));                                \
  float m0[4] = {-1e30f, -1e30f, -1e30f, -1e30f};                                      \
  float m1[4] = {-1e30f, -1e30f, -1e30f, -1e30f};                                      \
  _Pragma("unroll")                                                                    \
  for (int p = 0; p < 16; ++p) {                                                       \
    float dr = xhr - PRT[p], di = xhi - PIT[p];                                        \
    float met = -(dr * dr + di * di) * inoe;                                           \
    _Pragma("unroll")                                                                  \
    for (int k = 0; k < 4; ++k) {                                                      \
      if ((p >> (3 - k)) & 1) m1[k] = fmaxf(m1[k], met);                               \
      else                    m0[k] = fmaxf(m0[k], met);                               \
    }                                                                                  \
  }                                                                                    \
  _Pragma("unroll")                                                                    \
  for (int k = 0; k < 4; ++k) Lout[k] = m0[k] - m1[k];                                 \
}

// variable-node update for one float4 component C (codeword C of 4)
#define VUPD(C) {                                                                      \
  float p0 = pclip(P0.C, t0.C), p1 = pclip(P1.C, t1.C), p2 = pclip(P2.C, t2.C);        \
  float a0 = t0.C + p0, a1 = t1.C + p1, a2 = t2.C + p2;                                \
  float b0 = t0.C - p0, b1 = t1.C - p1, b2 = t2.C - p2;                                \
  float Ec = En.C;                                                                     \
  float A0 = Ec * (a1 * a2), A1 = Ec * (a0 * a2), A2 = Ec * (a0 * a1);                 \
  float B0 = b1 * b2,        B1 = b0 * b2,        B2 = b0 * b1;                        \
  n0.C = tfloor(__fdividef(A0 - B0, A0 + B0));                                         \
  n1.C = tfloor(__fdividef(A1 - B1, A1 + B1));                                         \
  n2.C = tfloor(__fdividef(A2 - B2, A2 + B2));                                         \
}

// ---------------- fused LMMSE + BP, ONE block per bt (4 codewords) ---------
// Round-18: 512 threads, ONE node + ONE check per thread (was 2+2 at 256).
// Round-17 showed the kernel is stall-bound (removing 35% of VALU work
// moved duration 3%): 13 waves/CU couldn't hide the barrier-bracketed
// LDS->VALU->LDS chains.  Same total work, half the per-thread critical
// path, double the waves: LDS 40 KB -> 4 blocks/CU x 8 waves = 32 waves/CU
// (HW max).  __launch_bounds__(512,4) leaves the allocator at natural ~56
// VGPR (R4 lesson: forcing the floor causes catastrophic spill); runtime
// occupancy is LDS-capped, not VGPR-capped.
__global__ void __launch_bounds__(512, 4)
k_fused(const float* __restrict__ h_re, const float* __restrict__ h_im,
        const float* __restrict__ n_re, const float* __restrict__ n_im,
        const double* __restrict__ nobuf,
        const unsigned* __restrict__ bpack, const unsigned* __restrict__ Ppack,
        const int* __restrict__ vlist, const int* __restrict__ coff,
        const int* __restrict__ cdend, const int* __restrict__ cperm,
        const int* __restrict__ cinfo, float* __restrict__ out, int ncw) {
  __shared__ float4 sT[EMAX];    // tanh(v2c/2) per edge slot x 4 cw (32 KB)
  __shared__ float4 sP[512];     // per-check product of tanh x 4 cw (8 KB)
  float4* sL = sT;               // staged LLRs alias (first NNODES entries)

  int tid = threadIdx.x;
  int bt = blockIdx.x;

  // ================= phase 1: LMMSE for this bt's 250 symbols ==============
  if (tid < NSYM) {
    int t = bt * NSYM + tid;
    int s = tid;

    float no = (float)nobuf[0];
    float sq = (float)nobuf[1];
    const float is2 = 0.70710678118654752f;  // 1/sqrt(2)

    float Hr[4][4], Hi[4][4];
    {
      const float4* hr4 = (const float4*)h_re;
      const float4* hi4 = (const float4*)h_im;
      #pragma unroll
      for (int i = 0; i < 4; ++i) {
        float4 a = hr4[t * 4 + i], c = hi4[t * 4 + i];
        Hr[i][0] = a.x * is2; Hr[i][1] = a.y * is2;
        Hr[i][2] = a.z * is2; Hr[i][3] = a.w * is2;
        Hi[i][0] = c.x * is2; Hi[i][1] = c.y * is2;
        Hi[i][2] = c.z * is2; Hi[i][3] = c.w * is2;
      }
    }

    // transmitted symbols: encode+map inline
    float xr[4], xi[4];
    #pragma unroll
    for (int ue = 0; ue < 4; ++ue) {
      const unsigned* bp = bpack + (bt * 4 + ue) * 16;
      int v = 0;
      #pragma unroll
      for (int k = 0; k < 4; ++k) {
        int n = 4 * s + k;
        int bit;
        if (n < KK) {
          bit = (bp[n >> 5] >> (n & 31)) & 1;
        } else {
          const unsigned* pp = Ppack + (n - KK) * 16;
          int cnt = 0;
          #pragma unroll
          for (int w = 0; w < 16; ++w) cnt += __popc(bp[w] & pp[w]);
          bit = cnt & 1;
        }
        v = (v << 1) | bit;  // MSB-first: weights 8,4,2,1
      }
      qam_pointf(v, xr[ue], xi[ue]);
    }

    // y = H x + w
    float yr[4], yi[4];
    {
      float4 wr = ((const float4*)n_re)[t];
      float4 wi = ((const float4*)n_im)[t];
      float wrv[4] = {wr.x, wr.y, wr.z, wr.w};
      float wiv[4] = {wi.x, wi.y, wi.z, wi.w};
      #pragma unroll
      for (int i = 0; i < 4; ++i) {
        float ar = wrv[i] * sq;
        float ai = wiv[i] * sq;
        #pragma unroll
        for (int j = 0; j < 4; ++j) {
          ar += Hr[i][j] * xr[j] - Hi[i][j] * xi[j];
          ai += Hr[i][j] * xi[j] + Hi[i][j] * xr[j];
        }
        yr[i] = ar; yi[i] = ai;
      }
    }

    // A = H H^H + no I, lower triangle, into scalars
    auto dotc = [&](int i, int j, float& ar, float& ai) {
      float r = 0.0f, m = 0.0f;
      #pragma unroll
      for (int k = 0; k < 4; ++k) {
        r += Hr[i][k] * Hr[j][k] + Hi[i][k] * Hi[j][k];
        m += Hi[i][k] * Hr[j][k] - Hr[i][k] * Hi[j][k];
      }
      ar = r; ai = m;
    };
    float a00, a11, a22, a33, dum;
    float a10r, a10i, a20r, a20i, a21r, a21i, a30r, a30i, a31r, a31i, a32r, a32i;
    dotc(0, 0, a00, dum);  a00 += no;
    dotc(1, 0, a10r, a10i);
    dotc(1, 1, a11, dum);  a11 += no;
    dotc(2, 0, a20r, a20i);
    dotc(2, 1, a21r, a21i);
    dotc(2, 2, a22, dum);  a22 += no;
    dotc(3, 0, a30r, a30i);
    dotc(3, 1, a31r, a31i);
    dotc(3, 2, a32r, a32i);
    dotc(3, 3, a33, dum);  a33 += no;

    // Cholesky in inverse-diagonal form
    float i00 = rsqrtf(a00);
    float L10r = a10r * i00, L10i = a10i * i00;
    float L20r = a20r * i00, L20i = a20i * i00;
    float L30r = a30r * i00, L30i = a30i * i00;
    float d11 = a11 - (L10r * L10r + L10i * L10i);
    float i11 = rsqrtf(d11);
    float L21r = (a21r - (L20r * L10r + L20i * L10i)) * i11;
    float L21i = (a21i - (L20i * L10r - L20r * L10i)) * i11;
    float L31r = (a31r - (L30r * L10r + L30i * L10i)) * i11;
    float L31i = (a31i - (L30i * L10r - L30r * L10i)) * i11;
    float d22 = a22 - (L20r * L20r + L20i * L20i) - (L21r * L21r + L21i * L21i);
    float i22 = rsqrtf(d22);
    float L32r = (a32r - (L30r * L20r + L30i * L20i) - (L31r * L21r + L31i * L21i)) * i22;
    float L32i = (a32i - (L30i * L20r - L30r * L20i) - (L31i * L21r - L31r * L21i)) * i22;
    float d33 = a33 - (L30r * L30r + L30i * L30i) - (L31r * L31r + L31i * L31i)
                    - (L32r * L32r + L32i * L32i);
    float i33 = rsqrtf(d33);

    // forward solve on y only: v = L^{-1} y (in place)
    {
      float v0r = yr[0] * i00,               v0i = yi[0] * i00;
      float v1r = (yr[1] - (L10r * v0r - L10i * v0i)) * i11;
      float v1i = (yi[1] - (L10r * v0i + L10i * v0r)) * i11;
      float v2r = (yr[2] - (L20r * v0r - L20i * v0i) - (L21r * v1r - L21i * v1i)) * i22;
      float v2i = (yi[2] - (L20r * v0i + L20i * v0r) - (L21r * v1i + L21i * v1r)) * i22;
      float v3r = (yr[3] - (L30r * v0r - L30i * v0i) - (L31r * v1r - L31i * v1i)
                         - (L32r * v2r - L32i * v2i)) * i33;
      float v3i = (yi[3] - (L30r * v0i + L30i * v0r) - (L31r * v1i + L31i * v1r)
                         - (L32r * v2i + L32i * v2r)) * i33;
      yr[0] = v0r; yi[0] = v0i; yr[1] = v1r; yi[1] = v1i;
      yr[2] = v2r; yi[2] = v2i; yr[3] = v3r; yi[3] = v3i;
    }

    // fp32 16-QAM table
    const float PRT[16] = { 0.31622776601683794f, 0.31622776601683794f, 0.9486832980505138f, 0.9486832980505138f,
                            0.31622776601683794f, 0.31622776601683794f, 0.9486832980505138f, 0.9486832980505138f,
                           -0.31622776601683794f,-0.31622776601683794f,-0.9486832980505138f,-0.9486832980505138f,
                           -0.31622776601683794f,-0.31622776601683794f,-0.9486832980505138f,-0.9486832980505138f };
    const float PIT[16] = { 0.31622776601683794f, 0.9486832980505138f, 0.31622776601683794f, 0.9486832980505138f,
                           -0.31622776601683794f,-0.9486832980505138f,-0.31622776601683794f,-0.9486832980505138f,
                            0.31622776601683794f, 0.9486832980505138f, 0.31622776601683794f, 0.9486832980505138f,
                           -0.31622776601683794f,-0.9486832980505138f,-0.31622776601683794f,-0.9486832980505138f };

    // all 4 UE columns (each feeds one codeword lane)
    float l0[4], l1[4], l2[4], l3[4];
    SOLVE_DEMAP(0, l0);
    SOLVE_DEMAP(1, l1);
    SOLVE_DEMAP(2, l2);
    SOLVE_DEMAP(3, l3);
    #pragma unroll
    for (int k = 0; k < 4; ++k) {
      sL[4 * s + k] = make_float4(l0[k], l1[k], l2[k], l3[k]);
    }
  }
  __syncthreads();

  // ================= phase 2: LDS-resident BP (4 codewords) ===============
  // ONE info node (n = tid) and ONE check (c = tid) per thread.
  int n = tid;
  bool iok = n < KK;
  float4 Ln = make_float4(0.f, 0.f, 0.f, 0.f);
  float4 En = make_float4(1.f, 1.f, 1.f, 1.f);
  int pk0 = 0, pk1 = 0, pk2 = 0;
  if (iok) {
    float4 L = sL[n];
    Ln = L;
    En = make_float4(__expf(fminf(fmaxf(L.x, -55.f), 55.f)),
                     __expf(fminf(fmaxf(L.y, -55.f), 55.f)),
                     __expf(fminf(fmaxf(L.z, -55.f), 55.f)),
                     __expf(fminf(fmaxf(L.w, -55.f), 55.f)));
    int s0 = vlist[n * MAXVDEG], s1 = vlist[n * MAXVDEG + 1], s2 = vlist[n * MAXVDEG + 2];
    pk0 = (cinfo[s0] & 0xffff0000) | SWZ(s0);
    pk1 = (cinfo[s1] & 0xffff0000) | SWZ(s1);
    pk2 = (cinfo[s2] & 0xffff0000) | SWZ(s2);
  }
  // per-check constant: tanh of the parity-node LLR.  Check tid (new id)
  // corresponds to ORIGINAL check cperm[tid]; its parity var is KK+orig.
  bool cok = tid < MM;
  float4 qpar = make_float4(1.f, 1.f, 1.f, 1.f);
  int beg = 0, dnd = 0;
  if (cok) {
    int oc = cperm[tid];
    qpar = tanh_half4(sL[KK + oc]);
    beg = coff[tid];
    dnd = cdend[tid];
  }
  __syncthreads();  // sL (= sT[0..1000)) reads done; sT writes may now begin

  for (int it = 0; it < NITERS; ++it) {
    // ---- pass 1: info-node var update ----
    if (it == 0) {
      if (iok) {
        float4 t = tanh_half4(Ln);
        sT[pk0 & 0xffff] = t;
        sT[pk1 & 0xffff] = t;
        sT[pk2 & 0xffff] = t;
      }
    } else {
      if (iok) {
        int s0 = pk0 & 0xffff, c0 = ((unsigned)pk0) >> 16;
        int s1 = pk1 & 0xffff, c1 = ((unsigned)pk1) >> 16;
        int s2 = pk2 & 0xffff, c2 = ((unsigned)pk2) >> 16;
        float4 P0 = sP[c0], P1 = sP[c1], P2 = sP[c2];
        float4 t0 = sT[s0], t1 = sT[s1], t2 = sT[s2];
        float4 n0, n1, n2;
        VUPD(x); VUPD(y); VUPD(z); VUPD(w);
        sT[s0] = n0;
        sT[s1] = n1;
        sT[s2] = n2;
      }
    }
    __syncthreads();
    // ---- pass 2: per-check products (parity factor from register) ----
    // Sorted checks: uniform trip counts per wave.
    if (cok) {
      float4 p = qpar;
      for (int e = beg; e < dnd; ++e) {
        float4 tt = sT[SWZ(e)];
        p.x *= tt.x; p.y *= tt.y; p.z *= tt.z; p.w *= tt.w;
      }
      sP[tid] = p;
    }
    __syncthreads();
  }

  // ---- decide: additive log form (once) ----
  int cw0 = bt * 4;
  float* o0 = out + (size_t)ncw * KK + (size_t)cw0 * KK;
  float* o1 = o0 + KK;
  float* o2 = o1 + KK;
  float* o3 = o2 + KK;
  if (iok) {
    int s0 = pk0 & 0xffff, c0 = ((unsigned)pk0) >> 16;
    int s1 = pk1 & 0xffff, c1 = ((unsigned)pk1) >> 16;
    int s2 = pk2 & 0xffff, c2 = ((unsigned)pk2) >> 16;
    float4 P0 = sP[c0], P1 = sP[c1], P2 = sP[c2];
    float4 t0 = sT[s0], t1 = sT[s1], t2 = sT[s2];
    float4 L = Ln;
    float ax = L.x + atanh2c(P0.x, t0.x) + atanh2c(P1.x, t1.x) + atanh2c(P2.x, t2.x);
    float ay = L.y + atanh2c(P0.y, t0.y) + atanh2c(P1.y, t1.y) + atanh2c(P2.y, t2.y);
    float az = L.z + atanh2c(P0.z, t0.z) + atanh2c(P1.z, t1.z) + atanh2c(P2.z, t2.z);
    float aw = L.w + atanh2c(P0.w, t0.w) + atanh2c(P1.w, t1.w) + atanh2c(P2.w, t2.w);
    o0[n] = (ax < 0.0f) ? 1.0f : 0.0f;
    o1[n] = (ay < 0.0f) ? 1.0f : 0.0f;
    o2[n] = (az < 0.0f) ? 1.0f : 0.0f;
    o3[n] = (aw < 0.0f) ? 1.0f : 0.0f;
  }
}

// ---------------- launcher ----------------
extern "C" void kernel_launch(void* const* d_in, const int* in_sizes, int n_in,
                              void* d_out, int out_size, void* d_ws, size_t ws_size,
                              hipStream_t stream) {
  const float* ebno = (const float*)d_in[1];
  const int*   b    = (const int*)d_in[2];
  const int*   P    = (const int*)d_in[3];
  const int*   cn   = (const int*)d_in[4];
  const int*   vn   = (const int*)d_in[5];
  const float* h_re = (const float*)d_in[6];
  const float* h_im = (const float*)d_in[7];
  const float* nre  = (const float*)d_in[8];
  const float* nim  = (const float*)d_in[9];
  float* out = (float*)d_out;

  int E     = in_sizes[4];
  int batch = in_sizes[2] / (4 * KK);
  int ncw   = batch * 4;

  char* ws = (char*)d_ws;
  size_t off = 0;
  auto alloc = [&](size_t bytes) -> void* {
    void* p = ws + off;
    off += (bytes + 255) & ~(size_t)255;
    return p;
  };
  unsigned* Ppack  = (unsigned*)alloc((size_t)MM * 16 * 4);
  unsigned* bpack  = (unsigned*)alloc((size_t)ncw * 16 * 4);
  int*      coff   = (int*)alloc((size_t)(MM + 1) * 4);
  int*      cdend  = (int*)alloc((size_t)MM * 4);
  int*      cperm  = (int*)alloc((size_t)MM * 4);
  int*      cinfo  = (int*)alloc((size_t)EMAX * 4);
  int*      vlist  = (int*)alloc((size_t)NNODES * MAXVDEG * 4);
  double*   nobuf  = (double*)alloc(2 * 8);
  (void)ws_size; (void)n_in; (void)out_size;

  int packItems  = MM * 16 + ncw * 16;
  int packBlocks = (packItems + 511) / 512;
  int bfBlocks   = (ncw * KK + 511) / 512;
  int setupGrid  = 1 + packBlocks + bfBlocks;

  k_setup<<<dim3(setupGrid), dim3(512), 0, stream>>>(cn, vn, E, ebno, P, b, ncw,
                                                     cinfo, vlist, coff, cdend, cperm,
                                                     nobuf, Ppack, bpack, out, packBlocks);
  k_fused<<<dim3(batch), dim3(512), 0, stream>>>(h_re, h_im, nre, nim, nobuf,
                                                 bpack, Ppack, vlist, coff, cdend,
                                                 cperm, cinfo, out, ncw);
}